// Round 8
// baseline (610.477 us; speedup 1.0000x reference)
//
#include <hip/hip_runtime.h>

#define NNODES 100000
#define NEDGES 1600000
#define DIM    128
#define OUTD   32
#define NGRAPH 512
#define LDA    136   // padded LDS stride (bf16 elems)

#define NBUCK2  256                          // coarse buckets: dst >> 9
#define BSHIFT  9
#define CAP     12288                        // per-bucket region capacity (mean 8163)
#define EPB2    8192
#define SBLOCKS ((NEDGES + EPB2 - 1) / EPB2) // 196
#define NBUILD  ((NNODES + 511) / 512)       // 196
#define FBLOCKS ((NNODES + 127) / 128)       // 782

using bf16x8 = __attribute__((ext_vector_type(8))) short;
using f32x4  = __attribute__((ext_vector_type(4))) float;

__device__ __forceinline__ short f2bf(float f) {
    unsigned u = __float_as_uint(f);
    unsigned r = (u + 0x7fff + ((u >> 16) & 1)) >> 16;   // RNE
    return (short)r;
}
__device__ __forceinline__ float bf2f(short s) {
    return __uint_as_float(((unsigned)(unsigned short)s) << 16);
}
__device__ __forceinline__ float bf2f_lo(unsigned u) { return __uint_as_float(u << 16); }
__device__ __forceinline__ float bf2f_hi(unsigned u) { return __uint_as_float(u & 0xffff0000u); }

// ============================================================
// Prep: weight transposes (bf16 W^T) + cursor init + pooled zero
// WT = [enc_W1, enc_W2, gcn_W0, gcn_W1, gcn_W2]
// ============================================================
__global__ __launch_bounds__(256) void k_prep(
    const float* __restrict__ eW1, const float* __restrict__ eW2,
    const float* __restrict__ gW, short* __restrict__ WT,
    int* __restrict__ gcur, float* __restrict__ pooled)
{
    int idx = blockIdx.x * 256 + threadIdx.x;
    if (idx < 5 * 16384) {
        int mat = idx >> 14, rem = idx & 16383;
        int k = rem >> 7, n = rem & 127;
        const float* src = (mat == 0) ? eW1 : (mat == 1) ? eW2
                                            : (gW + (size_t)(mat - 2) * 16384);
        WT[(size_t)mat * 16384 + n * DIM + k] = f2bf(src[k * DIM + n]);
    }
    if (idx < NBUCK2) gcur[idx] = idx * CAP;
    if (idx < NGRAPH * DIM) pooled[idx] = 0.f;
}

// ============================================================
// CSR build (block-local reservation scatter + per-bucket build)
// ============================================================
__global__ __launch_bounds__(512) void k_scatter(
    const int* __restrict__ src, const int* __restrict__ dst,
    int* __restrict__ gcur, unsigned* __restrict__ tmp)
{
    __shared__ unsigned short rnk[EPB2];
    __shared__ int h[NBUCK2];
    __shared__ int gbase[NBUCK2];
    const int tid  = threadIdx.x;
    const int base = blockIdx.x * EPB2;
    if (tid < NBUCK2) h[tid] = 0;
    __syncthreads();
    #pragma unroll
    for (int it = 0; it < EPB2 / 512; ++it) {
        int e = base + it * 512 + tid;
        if (e < NEDGES) {
            int b = dst[e] >> BSHIFT;
            rnk[it * 512 + tid] = (unsigned short)atomicAdd(&h[b], 1);
        }
    }
    __syncthreads();
    if (tid < NBUCK2 && h[tid] > 0)
        gbase[tid] = atomicAdd(&gcur[tid], h[tid]);
    __syncthreads();
    #pragma unroll
    for (int it = 0; it < EPB2 / 512; ++it) {
        int e = base + it * 512 + tid;
        if (e < NEDGES) {
            int d = dst[e], sv = src[e];
            int b = d >> BSHIFT;
            int pos = gbase[b] + rnk[it * 512 + tid];
            if (pos < (b + 1) * CAP)
                tmp[pos] = (unsigned)sv | ((unsigned)(d & 511) << 17);
        }
    }
}

__global__ __launch_bounds__(512) void k_build(
    const unsigned* __restrict__ tmp, const int* __restrict__ gcur,
    int* __restrict__ row_off, int* __restrict__ cntA,
    float* __restrict__ inv, int* __restrict__ col)
{
    __shared__ int hist[512], sc[512], lcur[512];
    const int tid   = threadIdx.x;
    const int b     = blockIdx.x;
    const int tbase = b * CAP;
    const int cnt_b = min(gcur[b] - tbase, CAP);
    hist[tid] = 0;
    __syncthreads();
    for (int i = tid; i < cnt_b; i += 512)
        atomicAdd(&hist[(tmp[tbase + i] >> 17) & 511], 1);
    __syncthreads();
    const int hv = hist[tid];
    sc[tid] = hv;
    __syncthreads();
    for (int off = 1; off < 512; off <<= 1) {
        int t = (tid >= off) ? sc[tid - off] : 0;
        __syncthreads();
        sc[tid] += t;
        __syncthreads();
    }
    const int start = tbase + sc[tid] - hv;
    lcur[tid] = start;
    const int node = b * 512 + tid;
    if (node < NNODES) {
        row_off[node] = start;
        cntA[node]    = hv;
        inv[node]     = rsqrtf((float)hv + 1.0f);
    }
    __syncthreads();
    for (int i = tid; i < cnt_b; i += 512) {
        unsigned t = tmp[tbase + i];
        int pos = atomicAdd(&lcur[(t >> 17) & 511], 1);
        col[pos] = (int)(t & 0x1FFFFu);
    }
}

// ============================================================
// Encoder: x -> relu(xW1+b1) -> relu(..W2+b2)*inv -> g0
// 512 thr / 128 rows; 2 chained MFMA GEMMs, h in LDS.
// ============================================================
__global__ __launch_bounds__(512, 4) void k_enc(
    const float* __restrict__ x, const short* __restrict__ WT,
    const float* __restrict__ b1, const float* __restrict__ b2,
    const float* __restrict__ inv, short* __restrict__ g0, int M)
{
    __shared__ short As[128 * LDA];
    __shared__ short Bs[128 * LDA];

    const int tid = threadIdx.x;
    const int m0  = blockIdx.x * 128;

    {
        const int row = tid >> 2, ch = (tid & 3) * 32;
        const int gr  = min(m0 + row, M - 1);
        const float4* sp = (const float4*)(x + (size_t)gr * DIM + ch);
        #pragma unroll
        for (int c = 0; c < 4; ++c) {
            float4 f0 = sp[c * 2], f1 = sp[c * 2 + 1];
            short t8[8] = { f2bf(f0.x), f2bf(f0.y), f2bf(f0.z), f2bf(f0.w),
                            f2bf(f1.x), f2bf(f1.y), f2bf(f1.z), f2bf(f1.w) };
            *(bf16x8*)&As[row * LDA + ch + c * 8] = *(bf16x8*)t8;
        }
    }

    const int wave = tid >> 6, lane = tid & 63;
    const int ml = lane & 15, quad = lane >> 4;
    const int w16 = wave * 16;
    const int brow = tid >> 2, bch = (tid & 3) * 32;

    #pragma unroll
    for (int mat = 0; mat < 2; ++mat) {
        if (mat > 0) __syncthreads();
        const short* wt = WT + (size_t)mat * 16384 + brow * DIM + bch;
        #pragma unroll
        for (int c = 0; c < 4; ++c)
            *(bf16x8*)&Bs[brow * LDA + bch + c * 8] = *(const bf16x8*)(wt + c * 8);
        __syncthreads();

        f32x4 acc[8] = {};
        #pragma unroll
        for (int kk = 0; kk < 4; ++kk) {
            const int k0 = kk * 32 + quad * 8;
            bf16x8 a = *(bf16x8*)&As[(w16 + ml) * LDA + k0];
            #pragma unroll
            for (int ni = 0; ni < 8; ++ni) {
                bf16x8 b = *(bf16x8*)&Bs[(ni * 16 + ml) * LDA + k0];
                acc[ni] = __builtin_amdgcn_mfma_f32_16x16x32_bf16(a, b, acc[ni], 0, 0, 0);
            }
        }
        #pragma unroll
        for (int ni = 0; ni < 8; ++ni) {
            const int colc = ni * 16 + ml;
            #pragma unroll
            for (int r = 0; r < 4; ++r) {
                const int rowl = w16 + quad * 4 + r;
                float v;
                if (mat == 0) {
                    v = fmaxf(acc[ni][r] + b1[colc], 0.f);
                } else {
                    v = fmaxf(acc[ni][r] + b2[colc], 0.f) * inv[min(m0 + rowl, M - 1)];
                }
                As[rowl * LDA + colc] = f2bf(v);
            }
        }
    }

    const int srow = w16 + (lane >> 2), sch = (lane & 3) * 32;
    const int grow = m0 + srow;
    if (grow < M) {
        #pragma unroll
        for (int c = 0; c < 4; ++c)
            *(bf16x8*)(g0 + (size_t)grow * DIM + sch + c * 8) =
                *(bf16x8*)&As[srow * LDA + sch + c * 8];
    }
}

// ============================================================
// Fused GCN layer (barrier-free): per wave, 16-node m-tile.
//   s[d]  = inv[d]*(g[d] + sum_src g[src])       (gather, 2 nodes/half-wave)
//   h'[d] = relu(s[d] @ W + b)                   (MFMA, B streamed from L2)
//   out   = OUT_G ? h'*inv : h'
// 512 thr, LDS = per-wave 16-row slices only, no __syncthreads.
// ============================================================
template<int OUT_G>
__global__ __launch_bounds__(512, 6) void k_layer(
    const short* __restrict__ g_in, const int* __restrict__ row_off,
    const int* __restrict__ cntA, const int* __restrict__ col,
    const float* __restrict__ inv, const float* __restrict__ bias,
    const short* __restrict__ WT, short* __restrict__ g_out)
{
    __shared__ short As[8 * 16 * LDA];   // 34.8 KB, wave-private slices
    const int tid  = threadIdx.x;
    const int wave = tid >> 6, lane = tid & 63;
    const int half = lane >> 5, sl = lane & 31;
    const int n0   = (blockIdx.x * 8 + wave) * 16;
    short* Aw = As + wave * 16 * LDA;

    const uint2* hp = (const uint2*)g_in;

    // ---- gather phase: 8 node-pairs, one node per half-wave ----
    #pragma unroll 1
    for (int p = 0; p < 8; ++p) {
        const int node = n0 + p * 2 + half;
        uint2 o = make_uint2(0u, 0u);
        if (node < NNODES) {
            uint2 us = hp[(size_t)node * 32 + sl];
            float a0 = bf2f_lo(us.x), a1 = bf2f_hi(us.x);
            float a2 = bf2f_lo(us.y), a3 = bf2f_hi(us.y);
            const int s = row_off[node];
            const int e = s + cntA[node];
            int j = s;
            for (; j + 3 < e; j += 4) {
                int u0 = col[j], u1 = col[j + 1], u2 = col[j + 2], u3 = col[j + 3];
                uint2 v0 = hp[(size_t)u0 * 32 + sl];
                uint2 v1 = hp[(size_t)u1 * 32 + sl];
                uint2 v2 = hp[(size_t)u2 * 32 + sl];
                uint2 v3 = hp[(size_t)u3 * 32 + sl];
                a0 += bf2f_lo(v0.x) + bf2f_lo(v1.x) + bf2f_lo(v2.x) + bf2f_lo(v3.x);
                a1 += bf2f_hi(v0.x) + bf2f_hi(v1.x) + bf2f_hi(v2.x) + bf2f_hi(v3.x);
                a2 += bf2f_lo(v0.y) + bf2f_lo(v1.y) + bf2f_lo(v2.y) + bf2f_lo(v3.y);
                a3 += bf2f_hi(v0.y) + bf2f_hi(v1.y) + bf2f_hi(v2.y) + bf2f_hi(v3.y);
            }
            for (; j < e; ++j) {
                uint2 v = hp[(size_t)col[j] * 32 + sl];
                a0 += bf2f_lo(v.x); a1 += bf2f_hi(v.x);
                a2 += bf2f_lo(v.y); a3 += bf2f_hi(v.y);
            }
            const float scv = inv[node];
            a0 *= scv; a1 *= scv; a2 *= scv; a3 *= scv;
            o.x = (unsigned)(unsigned short)f2bf(a0) |
                  ((unsigned)(unsigned short)f2bf(a1) << 16);
            o.y = (unsigned)(unsigned short)f2bf(a2) |
                  ((unsigned)(unsigned short)f2bf(a3) << 16);
        }
        *(uint2*)&Aw[(p * 2 + half) * LDA + sl * 4] = o;
    }

    // ---- MFMA phase: wave's 16-row tile @ W (B frags from global/L2) ----
    const int ml = lane & 15, quad = lane >> 4;
    f32x4 acc[8] = {};
    #pragma unroll
    for (int kk = 0; kk < 4; ++kk) {
        const int k0 = kk * 32 + quad * 8;
        bf16x8 a = *(bf16x8*)&Aw[ml * LDA + k0];
        #pragma unroll
        for (int ni = 0; ni < 8; ++ni) {
            bf16x8 b = *(const bf16x8*)(WT + (ni * 16 + ml) * DIM + k0);
            acc[ni] = __builtin_amdgcn_mfma_f32_16x16x32_bf16(a, b, acc[ni], 0, 0, 0);
        }
    }

    // ---- epilogue -> wave LDS slice -> coalesced store ----
    #pragma unroll
    for (int ni = 0; ni < 8; ++ni) {
        const int colc = ni * 16 + ml;
        #pragma unroll
        for (int r = 0; r < 4; ++r) {
            const int rowl = quad * 4 + r;
            float v = fmaxf(acc[ni][r] + bias[colc], 0.f);
            if (OUT_G) v *= inv[min(n0 + rowl, NNODES - 1)];
            Aw[rowl * LDA + colc] = f2bf(v);
        }
    }
    const int srow = lane >> 2, sch = (lane & 3) * 32;
    const int grow = n0 + srow;
    if (grow < NNODES) {
        #pragma unroll
        for (int c = 0; c < 4; ++c)
            *(bf16x8*)(g_out + (size_t)grow * DIM + sch + c * 8) =
                *(bf16x8*)&Aw[srow * LDA + sch + c * 8];
    }
}

// ============================================================
// Global add pool: segmented atomic reduction (batch sorted).
// ============================================================
__global__ __launch_bounds__(512) void k_pool(
    const short* __restrict__ h, const int* __restrict__ batch,
    float* __restrict__ pooled)
{
    const int wave = threadIdx.x >> 6, lane = threadIdx.x & 63;
    const int node0 = blockIdx.x * 128 + wave * 16;
    const unsigned* hp = (const unsigned*)h;

    float gx = 0.f, gy = 0.f;
    int cg = -1;
    #pragma unroll 1
    for (int i = 0; i < 16; ++i) {
        const int node = node0 + i;
        if (node >= NNODES) break;
        const int g = batch[node];
        if (g != cg) {
            if (cg >= 0) {
                atomicAdd(pooled + (size_t)cg * DIM + lane * 2,     gx);
                atomicAdd(pooled + (size_t)cg * DIM + lane * 2 + 1, gy);
            }
            cg = g; gx = 0.f; gy = 0.f;
        }
        unsigned v = hp[(size_t)node * 64 + lane];
        gx += bf2f_lo(v);
        gy += bf2f_hi(v);
    }
    if (cg >= 0) {
        atomicAdd(pooled + (size_t)cg * DIM + lane * 2,     gx);
        atomicAdd(pooled + (size_t)cg * DIM + lane * 2 + 1, gy);
    }
}

// ============================================================
// Fused decoder: out = relu(pooled@W1+b1)@W2 + b2   (4 blocks x 128 rows)
// ============================================================
__global__ __launch_bounds__(256) void k_dec(
    const float* __restrict__ A, const float* __restrict__ W1,
    const float* __restrict__ b1, const float* __restrict__ W2,
    const float* __restrict__ b2, float* __restrict__ out)
{
    __shared__ float As[16][132];
    __shared__ float Bs[16][132];
    __shared__ float T1[128][132];

    const int tid = threadIdx.x;
    const int m0  = blockIdx.x * 128;
    const int tx  = tid & 15;
    const int ty  = tid >> 4;
    const int ar = tid >> 2;
    const int ac = (tid & 3) << 2;
    const int br = tid >> 5;
    const int bc = (tid & 31) << 2;

    float acc[8][8];
    #pragma unroll
    for (int i = 0; i < 8; ++i)
        #pragma unroll
        for (int j = 0; j < 8; ++j) acc[i][j] = 0.f;

    for (int kt = 0; kt < 8; ++kt) {
        const int k0 = kt << 4;
        float4 a0 = *(const float4*)(A + (size_t)(m0 + ar)      * DIM + k0 + ac);
        float4 a1 = *(const float4*)(A + (size_t)(m0 + ar + 64) * DIM + k0 + ac);
        float4 b0 = *(const float4*)(W1 + (size_t)(k0 + br)     * DIM + bc);
        float4 b1v= *(const float4*)(W1 + (size_t)(k0 + br + 8) * DIM + bc);

        __syncthreads();
        As[ac + 0][ar] = a0.x; As[ac + 1][ar] = a0.y;
        As[ac + 2][ar] = a0.z; As[ac + 3][ar] = a0.w;
        As[ac + 0][ar + 64] = a1.x; As[ac + 1][ar + 64] = a1.y;
        As[ac + 2][ar + 64] = a1.z; As[ac + 3][ar + 64] = a1.w;
        *(float4*)&Bs[br][bc]     = b0;
        *(float4*)&Bs[br + 8][bc] = b1v;
        __syncthreads();

        #pragma unroll
        for (int kk = 0; kk < 16; ++kk) {
            float4 fa0 = *(const float4*)&As[kk][ty * 8];
            float4 fa1 = *(const float4*)&As[kk][ty * 8 + 4];
            float4 fb0 = *(const float4*)&Bs[kk][tx * 8];
            float4 fb1 = *(const float4*)&Bs[kk][tx * 8 + 4];
            float av[8] = {fa0.x, fa0.y, fa0.z, fa0.w, fa1.x, fa1.y, fa1.z, fa1.w};
            float bv[8] = {fb0.x, fb0.y, fb0.z, fb0.w, fb1.x, fb1.y, fb1.z, fb1.w};
            #pragma unroll
            for (int i = 0; i < 8; ++i)
                #pragma unroll
                for (int j = 0; j < 8; ++j)
                    acc[i][j] = fmaf(av[i], bv[j], acc[i][j]);
        }
    }

    float4 bb0 = *(const float4*)(b1 + tx * 8);
    float4 bb1 = *(const float4*)(b1 + tx * 8 + 4);
    float bcol[8] = {bb0.x, bb0.y, bb0.z, bb0.w, bb1.x, bb1.y, bb1.z, bb1.w};

    #pragma unroll
    for (int i = 0; i < 8; ++i) {
        const int rl = ty * 8 + i;
        #pragma unroll
        for (int j = 0; j < 8; ++j)
            T1[rl][tx * 8 + j] = fmaxf(acc[i][j] + bcol[j], 0.f);
    }
    __syncthreads();

    // stage 2: out[128 x 32]
    const int c  = tid & 31;
    const int rg = tid >> 5;        // 0..7
    #pragma unroll 1
    for (int j = 0; j < 16; ++j) {
        const int r = rg + j * 8;
        float a2 = b2[c];
        #pragma unroll 8
        for (int k = 0; k < DIM; ++k)
            a2 = fmaf(T1[r][k], W2[(size_t)k * OUTD + c], a2);
        out[(size_t)(m0 + r) * OUTD + c] = a2;
    }
}

// ============================================================
extern "C" void kernel_launch(void* const* d_in, const int* in_sizes, int n_in,
                              void* d_out, int out_size, void* d_ws, size_t ws_size,
                              hipStream_t stream)
{
    const float* x      = (const float*)d_in[0];
    const int*   ei     = (const int*)d_in[1];
    const int*   batch  = (const int*)d_in[2];
    const float* enc_W1 = (const float*)d_in[3];
    const float* enc_b1 = (const float*)d_in[4];
    const float* enc_W2 = (const float*)d_in[5];
    const float* enc_b2 = (const float*)d_in[6];
    const float* gcn_W  = (const float*)d_in[7];
    const float* gcn_b  = (const float*)d_in[8];
    const float* dec_W1 = (const float*)d_in[9];
    const float* dec_b1 = (const float*)d_in[10];
    const float* dec_W2 = (const float*)d_in[11];
    const float* dec_b2 = (const float*)d_in[12];
    float* out = (float*)d_out;

    const int* src = ei;
    const int* dst = ei + NEDGES;

    char* p = (char*)d_ws;
    auto alloc = [&](size_t bytes) -> void* {
        void* r = (void*)p;
        p += (bytes + 255) & ~(size_t)255;
        return r;
    };
    short*    hwA    = (short*)   alloc((size_t)NNODES * DIM * sizeof(short));
    short*    hwB    = (short*)   alloc((size_t)NNODES * DIM * sizeof(short));
    float*    inv    = (float*)   alloc((size_t)NNODES * sizeof(float));
    int*      row_off= (int*)     alloc((size_t)NNODES * sizeof(int));
    int*      cntA   = (int*)     alloc((size_t)NNODES * sizeof(int));
    int*      col    = (int*)     alloc((size_t)NBUCK2 * CAP * sizeof(int));
    unsigned* tmp    = (unsigned*)alloc((size_t)NBUCK2 * CAP * sizeof(unsigned));
    int*      gcur   = (int*)     alloc((size_t)NBUCK2 * sizeof(int));
    short*    WT     = (short*)   alloc((size_t)5 * DIM * DIM * sizeof(short));
    float*    pooled = (float*)   alloc((size_t)NGRAPH * DIM * sizeof(float));

    // ---- prep + CSR build ----
    k_prep   <<<(5 * 16384 + 255) / 256, 256, 0, stream>>>(enc_W1, enc_W2, gcn_W,
                                                           WT, gcur, pooled);
    k_scatter<<<SBLOCKS, 512, 0, stream>>>(src, dst, gcur, tmp);
    k_build  <<<NBUILD, 512, 0, stream>>>(tmp, gcur, row_off, cntA, inv, col);

    // ---- encoder: x -> g0 (= h_enc * inv) ----
    k_enc<<<FBLOCKS, 512, 0, stream>>>(x, WT, enc_b1, enc_b2, inv, hwA, NNODES);

    // ---- fused GCN layers (gather -> MFMA, no barriers) ----
    k_layer<1><<<FBLOCKS, 512, 0, stream>>>(hwA, row_off, cntA, col, inv,
                                            gcn_b,       WT + 2 * 16384, hwB);
    k_layer<1><<<FBLOCKS, 512, 0, stream>>>(hwB, row_off, cntA, col, inv,
                                            gcn_b + 128, WT + 3 * 16384, hwA);
    k_layer<0><<<FBLOCKS, 512, 0, stream>>>(hwA, row_off, cntA, col, inv,
                                            gcn_b + 256, WT + 4 * 16384, hwB);

    // ---- pool + decoder ----
    k_pool<<<FBLOCKS, 512, 0, stream>>>(hwB, batch, pooled);
    k_dec <<<(NGRAPH + 127) / 128, 256, 0, stream>>>(pooled, dec_W1, dec_b1,
                                                     dec_W2, dec_b2, out);
}

// Round 9
// 470.793 us; speedup vs baseline: 1.2967x; 1.2967x over previous
//
#include <hip/hip_runtime.h>

#define NNODES 100000
#define NEDGES 1600000
#define DIM    128
#define OUTD   32
#define NGRAPH 512
#define LDA    136   // padded LDS stride (bf16 elems)

#define NBUCK2  256                          // coarse buckets: dst >> 9
#define BSHIFT  9
#define CAP     12288                        // per-bucket region capacity (mean 8163)
#define EPB2    8192
#define SBLOCKS ((NEDGES + EPB2 - 1) / EPB2) // 196
#define NBUILD  ((NNODES + 511) / 512)       // 196
#define FBLOCKS ((NNODES + 127) / 128)       // 782

using bf16x8 = __attribute__((ext_vector_type(8))) short;
using f32x4  = __attribute__((ext_vector_type(4))) float;

__device__ __forceinline__ short f2bf(float f) {
    unsigned u = __float_as_uint(f);
    unsigned r = (u + 0x7fff + ((u >> 16) & 1)) >> 16;   // RNE
    return (short)r;
}
__device__ __forceinline__ float bf2f(short s) {
    return __uint_as_float(((unsigned)(unsigned short)s) << 16);
}
__device__ __forceinline__ float bf2f_lo(unsigned u) { return __uint_as_float(u << 16); }
__device__ __forceinline__ float bf2f_hi(unsigned u) { return __uint_as_float(u & 0xffff0000u); }

// ============================================================
// Prep: weight transposes (bf16 W^T) + cursor init + pooled zero
// WT = [enc_W1, enc_W2, gcn_W0, gcn_W1, gcn_W2]
// ============================================================
__global__ __launch_bounds__(256) void k_prep(
    const float* __restrict__ eW1, const float* __restrict__ eW2,
    const float* __restrict__ gW, short* __restrict__ WT,
    int* __restrict__ gcur, float* __restrict__ pooled)
{
    int idx = blockIdx.x * 256 + threadIdx.x;
    if (idx < 5 * 16384) {
        int mat = idx >> 14, rem = idx & 16383;
        int k = rem >> 7, n = rem & 127;
        const float* src = (mat == 0) ? eW1 : (mat == 1) ? eW2
                                            : (gW + (size_t)(mat - 2) * 16384);
        WT[(size_t)mat * 16384 + n * DIM + k] = f2bf(src[k * DIM + n]);
    }
    if (idx < NBUCK2) gcur[idx] = idx * CAP;
    if (idx < NGRAPH * DIM) pooled[idx] = 0.f;
}

// ============================================================
// CSR build (block-local reservation scatter + per-bucket build)
// ============================================================
__global__ __launch_bounds__(512) void k_scatter(
    const int* __restrict__ src, const int* __restrict__ dst,
    int* __restrict__ gcur, unsigned* __restrict__ tmp)
{
    __shared__ unsigned short rnk[EPB2];
    __shared__ int h[NBUCK2];
    __shared__ int gbase[NBUCK2];
    const int tid  = threadIdx.x;
    const int base = blockIdx.x * EPB2;
    if (tid < NBUCK2) h[tid] = 0;
    __syncthreads();
    #pragma unroll
    for (int it = 0; it < EPB2 / 512; ++it) {
        int e = base + it * 512 + tid;
        if (e < NEDGES) {
            int b = dst[e] >> BSHIFT;
            rnk[it * 512 + tid] = (unsigned short)atomicAdd(&h[b], 1);
        }
    }
    __syncthreads();
    if (tid < NBUCK2 && h[tid] > 0)
        gbase[tid] = atomicAdd(&gcur[tid], h[tid]);
    __syncthreads();
    #pragma unroll
    for (int it = 0; it < EPB2 / 512; ++it) {
        int e = base + it * 512 + tid;
        if (e < NEDGES) {
            int d = dst[e], sv = src[e];
            int b = d >> BSHIFT;
            int pos = gbase[b] + rnk[it * 512 + tid];
            if (pos < (b + 1) * CAP)
                tmp[pos] = (unsigned)sv | ((unsigned)(d & 511) << 17);
        }
    }
}

__global__ __launch_bounds__(512) void k_build(
    const unsigned* __restrict__ tmp, const int* __restrict__ gcur,
    int* __restrict__ row_off, int* __restrict__ cntA,
    float* __restrict__ inv, int* __restrict__ col)
{
    __shared__ int hist[512], sc[512], lcur[512];
    const int tid   = threadIdx.x;
    const int b     = blockIdx.x;
    const int tbase = b * CAP;
    const int cnt_b = min(gcur[b] - tbase, CAP);
    hist[tid] = 0;
    __syncthreads();
    for (int i = tid; i < cnt_b; i += 512)
        atomicAdd(&hist[(tmp[tbase + i] >> 17) & 511], 1);
    __syncthreads();
    const int hv = hist[tid];
    sc[tid] = hv;
    __syncthreads();
    for (int off = 1; off < 512; off <<= 1) {
        int t = (tid >= off) ? sc[tid - off] : 0;
        __syncthreads();
        sc[tid] += t;
        __syncthreads();
    }
    const int start = tbase + sc[tid] - hv;
    lcur[tid] = start;
    const int node = b * 512 + tid;
    if (node < NNODES) {
        row_off[node] = start;
        cntA[node]    = hv;
        inv[node]     = rsqrtf((float)hv + 1.0f);
    }
    __syncthreads();
    for (int i = tid; i < cnt_b; i += 512) {
        unsigned t = tmp[tbase + i];
        int pos = atomicAdd(&lcur[(t >> 17) & 511], 1);
        col[pos] = (int)(t & 0x1FFFFu);
    }
}

// ============================================================
// Fused encoder: x -> relu(xW1+b1) -> relu(..W2+b2) -> (..Wg0)*inv -> hw0
// 512 thr / 128 rows; 3 chained MFMA GEMMs, h in LDS. (r7 version)
// ============================================================
__global__ __launch_bounds__(512, 4) void k_enc(
    const float* __restrict__ x, const short* __restrict__ WT,
    const float* __restrict__ b1, const float* __restrict__ b2,
    const float* __restrict__ inv, short* __restrict__ hw0, int M)
{
    __shared__ short As[128 * LDA];
    __shared__ short Bs[128 * LDA];

    const int tid = threadIdx.x;
    const int m0  = blockIdx.x * 128;

    {
        const int row = tid >> 2, ch = (tid & 3) * 32;
        const int gr  = min(m0 + row, M - 1);
        const float4* sp = (const float4*)(x + (size_t)gr * DIM + ch);
        #pragma unroll
        for (int c = 0; c < 4; ++c) {
            float4 f0 = sp[c * 2], f1 = sp[c * 2 + 1];
            short t8[8] = { f2bf(f0.x), f2bf(f0.y), f2bf(f0.z), f2bf(f0.w),
                            f2bf(f1.x), f2bf(f1.y), f2bf(f1.z), f2bf(f1.w) };
            *(bf16x8*)&As[row * LDA + ch + c * 8] = *(bf16x8*)t8;
        }
    }

    const int wave = tid >> 6, lane = tid & 63;
    const int ml = lane & 15, quad = lane >> 4;
    const int w16 = wave * 16;
    const int brow = tid >> 2, bch = (tid & 3) * 32;

    #pragma unroll
    for (int mat = 0; mat < 3; ++mat) {
        if (mat > 0) __syncthreads();
        const short* wt = WT + (size_t)mat * 16384 + brow * DIM + bch;
        #pragma unroll
        for (int c = 0; c < 4; ++c)
            *(bf16x8*)&Bs[brow * LDA + bch + c * 8] = *(const bf16x8*)(wt + c * 8);
        __syncthreads();

        f32x4 acc[8] = {};
        #pragma unroll
        for (int kk = 0; kk < 4; ++kk) {
            const int k0 = kk * 32 + quad * 8;
            bf16x8 a = *(bf16x8*)&As[(w16 + ml) * LDA + k0];
            #pragma unroll
            for (int ni = 0; ni < 8; ++ni) {
                bf16x8 b = *(bf16x8*)&Bs[(ni * 16 + ml) * LDA + k0];
                acc[ni] = __builtin_amdgcn_mfma_f32_16x16x32_bf16(a, b, acc[ni], 0, 0, 0);
            }
        }
        #pragma unroll
        for (int ni = 0; ni < 8; ++ni) {
            const int colc = ni * 16 + ml;
            #pragma unroll
            for (int r = 0; r < 4; ++r) {
                const int rowl = w16 + quad * 4 + r;
                float v = acc[ni][r];
                if (mat == 0)      v = fmaxf(v + b1[colc], 0.f);
                else if (mat == 1) v = fmaxf(v + b2[colc], 0.f);
                else               v *= inv[min(m0 + rowl, M - 1)];
                As[rowl * LDA + colc] = f2bf(v);
            }
        }
    }

    const int srow = w16 + (lane >> 2), sch = (lane & 3) * 32;
    const int grow = m0 + srow;
    if (grow < M) {
        #pragma unroll
        for (int c = 0; c < 4; ++c)
            *(bf16x8*)(hw0 + (size_t)grow * DIM + sch + c * 8) =
                *(bf16x8*)&As[srow * LDA + sch + c * 8];
    }
}

// ============================================================
// gemm_mfma v2: C = (A @ W)*inv[row], W as bf16 W^T.
// Bs-only LDS (34.8 KB -> 4 blocks/CU); A-frags loaded direct from
// global (64B-coalesced per 4 lanes); epilogue reuses Bs after barrier.
// ============================================================
__global__ __launch_bounds__(256) void gemm_mfma(
    const short* __restrict__ A, const short* __restrict__ WT,
    const float* __restrict__ inv, short* __restrict__ C, int M)
{
    __shared__ short Bs[128 * LDA];

    const int tid = threadIdx.x;
    const int m0  = blockIdx.x * 128;

    #pragma unroll
    for (int i = 0; i < 8; ++i) {
        int idx = tid + i * 256;
        int n = idx >> 4, kg = (idx & 15) << 3;
        *(bf16x8*)&Bs[n * LDA + kg] = *(const bf16x8*)(WT + n * DIM + kg);
    }
    __syncthreads();

    const int wave = tid >> 6, lane = tid & 63;
    const int ml = lane & 15, quad = lane >> 4;
    const int w32 = wave * 32;

    f32x4 acc[2][8] = {};
    #pragma unroll
    for (int kk = 0; kk < 4; ++kk) {
        const int k0 = kk * 32 + quad * 8;
        const int r0 = min(m0 + w32 + ml,      M - 1);
        const int r1 = min(m0 + w32 + 16 + ml, M - 1);
        bf16x8 a0 = *(const bf16x8*)(A + (size_t)r0 * DIM + k0);
        bf16x8 a1 = *(const bf16x8*)(A + (size_t)r1 * DIM + k0);
        #pragma unroll
        for (int ni = 0; ni < 8; ++ni) {
            bf16x8 b = *(bf16x8*)&Bs[(ni * 16 + ml) * LDA + k0];
            acc[0][ni] = __builtin_amdgcn_mfma_f32_16x16x32_bf16(a0, b, acc[0][ni], 0, 0, 0);
            acc[1][ni] = __builtin_amdgcn_mfma_f32_16x16x32_bf16(a1, b, acc[1][ni], 0, 0, 0);
        }
    }
    __syncthreads();   // everyone done reading Bs -> reuse as C staging

    #pragma unroll
    for (int mi = 0; mi < 2; ++mi) {
        #pragma unroll
        for (int ni = 0; ni < 8; ++ni) {
            const int colc = ni * 16 + ml;
            #pragma unroll
            for (int r = 0; r < 4; ++r) {
                const int row = w32 + mi * 16 + quad * 4 + r;
                float v = acc[mi][ni][r] * inv[min(m0 + row, M - 1)];
                Bs[row * LDA + colc] = f2bf(v);
            }
        }
    }
    __syncthreads();
    #pragma unroll
    for (int i = 0; i < 2; ++i) {
        const int srow = w32 + i * 16 + (lane >> 2);
        const int sch  = (lane & 3) * 32;
        const int grow = m0 + srow;
        if (grow < M) {
            #pragma unroll
            for (int c = 0; c < 4; ++c)
                *(bf16x8*)(C + (size_t)grow * DIM + sch + c * 8) =
                    *(bf16x8*)&Bs[srow * LDA + sch + c * 8];
        }
    }
}

// ============================================================
// Aggregation: 2 nodes per wave, 32 lanes x uint2 (8B) per node. (r7)
// ============================================================
__global__ __launch_bounds__(512) void k_agg(
    const short* __restrict__ hwp, const int* __restrict__ row_off,
    const int* __restrict__ cntA, const int* __restrict__ col,
    const float* __restrict__ inv, const float* __restrict__ bias,
    short* __restrict__ hout)
{
    const int wid  = blockIdx.x * 8 + (threadIdx.x >> 6);
    const int lane = threadIdx.x & 63;
    const int half = lane >> 5;
    const int sl   = lane & 31;
    const int node = wid * 2 + half;
    if (node >= NNODES) return;

    const uint2* hp = (const uint2*)hwp;
    uint2 us = hp[(size_t)node * 32 + sl];
    float a0 = bf2f_lo(us.x), a1 = bf2f_hi(us.x);
    float a2 = bf2f_lo(us.y), a3 = bf2f_hi(us.y);

    const int s = row_off[node];
    const int e = s + cntA[node];
    int j = s;
    for (; j + 3 < e; j += 4) {
        int u0 = col[j], u1 = col[j + 1], u2 = col[j + 2], u3 = col[j + 3];
        uint2 v0 = hp[(size_t)u0 * 32 + sl];
        uint2 v1 = hp[(size_t)u1 * 32 + sl];
        uint2 v2 = hp[(size_t)u2 * 32 + sl];
        uint2 v3 = hp[(size_t)u3 * 32 + sl];
        a0 += bf2f_lo(v0.x) + bf2f_lo(v1.x) + bf2f_lo(v2.x) + bf2f_lo(v3.x);
        a1 += bf2f_hi(v0.x) + bf2f_hi(v1.x) + bf2f_hi(v2.x) + bf2f_hi(v3.x);
        a2 += bf2f_lo(v0.y) + bf2f_lo(v1.y) + bf2f_lo(v2.y) + bf2f_lo(v3.y);
        a3 += bf2f_hi(v0.y) + bf2f_hi(v1.y) + bf2f_hi(v2.y) + bf2f_hi(v3.y);
    }
    for (; j < e; ++j) {
        uint2 v = hp[(size_t)col[j] * 32 + sl];
        a0 += bf2f_lo(v.x); a1 += bf2f_hi(v.x);
        a2 += bf2f_lo(v.y); a3 += bf2f_hi(v.y);
    }
    const float scv = inv[node];
    const float4 bb = ((const float4*)bias)[sl];
    float o0 = fmaxf(fmaf(a0, scv, bb.x), 0.f);
    float o1 = fmaxf(fmaf(a1, scv, bb.y), 0.f);
    float o2 = fmaxf(fmaf(a2, scv, bb.z), 0.f);
    float o3 = fmaxf(fmaf(a3, scv, bb.w), 0.f);
    uint2 o;
    o.x = (unsigned)(unsigned short)f2bf(o0) | ((unsigned)(unsigned short)f2bf(o1) << 16);
    o.y = (unsigned)(unsigned short)f2bf(o2) | ((unsigned)(unsigned short)f2bf(o3) << 16);
    ((uint2*)hout)[(size_t)node * 32 + sl] = o;
}

// ============================================================
// Global add pool: segmented atomic reduction (batch sorted). (r7)
// ============================================================
__global__ __launch_bounds__(512) void k_pool(
    const short* __restrict__ h, const int* __restrict__ batch,
    float* __restrict__ pooled)
{
    const int wave = threadIdx.x >> 6, lane = threadIdx.x & 63;
    const int node0 = blockIdx.x * 128 + wave * 16;
    const unsigned* hp = (const unsigned*)h;

    float gx = 0.f, gy = 0.f;
    int cg = -1;
    #pragma unroll 1
    for (int i = 0; i < 16; ++i) {
        const int node = node0 + i;
        if (node >= NNODES) break;
        const int g = batch[node];
        if (g != cg) {
            if (cg >= 0) {
                atomicAdd(pooled + (size_t)cg * DIM + lane * 2,     gx);
                atomicAdd(pooled + (size_t)cg * DIM + lane * 2 + 1, gy);
            }
            cg = g; gx = 0.f; gy = 0.f;
        }
        unsigned v = hp[(size_t)node * 64 + lane];
        gx += bf2f_lo(v);
        gy += bf2f_hi(v);
    }
    if (cg >= 0) {
        atomicAdd(pooled + (size_t)cg * DIM + lane * 2,     gx);
        atomicAdd(pooled + (size_t)cg * DIM + lane * 2 + 1, gy);
    }
}

// ============================================================
// Fused decoder: out = relu(pooled@W1+b1)@W2 + b2   (4 blocks x 128 rows)
// ============================================================
__global__ __launch_bounds__(256) void k_dec(
    const float* __restrict__ A, const float* __restrict__ W1,
    const float* __restrict__ b1, const float* __restrict__ W2,
    const float* __restrict__ b2, float* __restrict__ out)
{
    __shared__ float As[16][132];
    __shared__ float Bs[16][132];
    __shared__ float T1[128][132];

    const int tid = threadIdx.x;
    const int m0  = blockIdx.x * 128;
    const int tx  = tid & 15;
    const int ty  = tid >> 4;
    const int ar = tid >> 2;
    const int ac = (tid & 3) << 2;
    const int br = tid >> 5;
    const int bc = (tid & 31) << 2;

    float acc[8][8];
    #pragma unroll
    for (int i = 0; i < 8; ++i)
        #pragma unroll
        for (int j = 0; j < 8; ++j) acc[i][j] = 0.f;

    for (int kt = 0; kt < 8; ++kt) {
        const int k0 = kt << 4;
        float4 a0 = *(const float4*)(A + (size_t)(m0 + ar)      * DIM + k0 + ac);
        float4 a1 = *(const float4*)(A + (size_t)(m0 + ar + 64) * DIM + k0 + ac);
        float4 b0 = *(const float4*)(W1 + (size_t)(k0 + br)     * DIM + bc);
        float4 b1v= *(const float4*)(W1 + (size_t)(k0 + br + 8) * DIM + bc);

        __syncthreads();
        As[ac + 0][ar] = a0.x; As[ac + 1][ar] = a0.y;
        As[ac + 2][ar] = a0.z; As[ac + 3][ar] = a0.w;
        As[ac + 0][ar + 64] = a1.x; As[ac + 1][ar + 64] = a1.y;
        As[ac + 2][ar + 64] = a1.z; As[ac + 3][ar + 64] = a1.w;
        *(float4*)&Bs[br][bc]     = b0;
        *(float4*)&Bs[br + 8][bc] = b1v;
        __syncthreads();

        #pragma unroll
        for (int kk = 0; kk < 16; ++kk) {
            float4 fa0 = *(const float4*)&As[kk][ty * 8];
            float4 fa1 = *(const float4*)&As[kk][ty * 8 + 4];
            float4 fb0 = *(const float4*)&Bs[kk][tx * 8];
            float4 fb1 = *(const float4*)&Bs[kk][tx * 8 + 4];
            float av[8] = {fa0.x, fa0.y, fa0.z, fa0.w, fa1.x, fa1.y, fa1.z, fa1.w};
            float bv[8] = {fb0.x, fb0.y, fb0.z, fb0.w, fb1.x, fb1.y, fb1.z, fb1.w};
            #pragma unroll
            for (int i = 0; i < 8; ++i)
                #pragma unroll
                for (int j = 0; j < 8; ++j)
                    acc[i][j] = fmaf(av[i], bv[j], acc[i][j]);
        }
    }

    float4 bb0 = *(const float4*)(b1 + tx * 8);
    float4 bb1 = *(const float4*)(b1 + tx * 8 + 4);
    float bcol[8] = {bb0.x, bb0.y, bb0.z, bb0.w, bb1.x, bb1.y, bb1.z, bb1.w};

    #pragma unroll
    for (int i = 0; i < 8; ++i) {
        const int rl = ty * 8 + i;
        #pragma unroll
        for (int j = 0; j < 8; ++j)
            T1[rl][tx * 8 + j] = fmaxf(acc[i][j] + bcol[j], 0.f);
    }
    __syncthreads();

    const int c  = tid & 31;
    const int rg = tid >> 5;
    #pragma unroll 1
    for (int j = 0; j < 16; ++j) {
        const int r = rg + j * 8;
        float a2 = b2[c];
        #pragma unroll 8
        for (int k = 0; k < DIM; ++k)
            a2 = fmaf(T1[r][k], W2[(size_t)k * OUTD + c], a2);
        out[(size_t)(m0 + r) * OUTD + c] = a2;
    }
}

// ============================================================
extern "C" void kernel_launch(void* const* d_in, const int* in_sizes, int n_in,
                              void* d_out, int out_size, void* d_ws, size_t ws_size,
                              hipStream_t stream)
{
    const float* x      = (const float*)d_in[0];
    const int*   ei     = (const int*)d_in[1];
    const int*   batch  = (const int*)d_in[2];
    const float* enc_W1 = (const float*)d_in[3];
    const float* enc_b1 = (const float*)d_in[4];
    const float* enc_W2 = (const float*)d_in[5];
    const float* enc_b2 = (const float*)d_in[6];
    const float* gcn_W  = (const float*)d_in[7];
    const float* gcn_b  = (const float*)d_in[8];
    const float* dec_W1 = (const float*)d_in[9];
    const float* dec_b1 = (const float*)d_in[10];
    const float* dec_W2 = (const float*)d_in[11];
    const float* dec_b2 = (const float*)d_in[12];
    float* out = (float*)d_out;

    const int* src = ei;
    const int* dst = ei + NEDGES;

    char* p = (char*)d_ws;
    auto alloc = [&](size_t bytes) -> void* {
        void* r = (void*)p;
        p += (bytes + 255) & ~(size_t)255;
        return r;
    };
    short*    hwA    = (short*)   alloc((size_t)NNODES * DIM * sizeof(short));
    short*    hwB    = (short*)   alloc((size_t)NNODES * DIM * sizeof(short));
    float*    inv    = (float*)   alloc((size_t)NNODES * sizeof(float));
    int*      row_off= (int*)     alloc((size_t)NNODES * sizeof(int));
    int*      cntA   = (int*)     alloc((size_t)NNODES * sizeof(int));
    int*      col    = (int*)     alloc((size_t)NBUCK2 * CAP * sizeof(int));
    unsigned* tmp    = (unsigned*)alloc((size_t)NBUCK2 * CAP * sizeof(unsigned));
    int*      gcur   = (int*)     alloc((size_t)NBUCK2 * sizeof(int));
    short*    WT     = (short*)   alloc((size_t)5 * DIM * DIM * sizeof(short));
    float*    pooled = (float*)   alloc((size_t)NGRAPH * DIM * sizeof(float));

    // ---- prep + CSR build ----
    k_prep   <<<(5 * 16384 + 255) / 256, 256, 0, stream>>>(enc_W1, enc_W2, gcn_W,
                                                           WT, gcur, pooled);
    k_scatter<<<SBLOCKS, 512, 0, stream>>>(src, dst, gcur, tmp);
    k_build  <<<NBUILD, 512, 0, stream>>>(tmp, gcur, row_off, cntA, inv, col);

    // ---- fused encoder: x -> hw0 ----
    k_enc<<<FBLOCKS, 512, 0, stream>>>(x, WT, enc_b1, enc_b2, inv, hwA, NNODES);

    // ---- GCN layers: agg (hwA->hwB) then gemm (hwB->hwA) ----
    const int aggBlocks = (NNODES + 15) / 16;
    k_agg<<<aggBlocks, 512, 0, stream>>>(hwA, row_off, cntA, col, inv, gcn_b, hwB);
    gemm_mfma<<<FBLOCKS, 256, 0, stream>>>(hwB, WT + 3 * 16384, inv, hwA, NNODES);
    k_agg<<<aggBlocks, 512, 0, stream>>>(hwA, row_off, cntA, col, inv, gcn_b + 128, hwB);
    gemm_mfma<<<FBLOCKS, 256, 0, stream>>>(hwB, WT + 4 * 16384, inv, hwA, NNODES);
    k_agg<<<aggBlocks, 512, 0, stream>>>(hwA, row_off, cntA, col, inv, gcn_b + 256, hwB);

    // ---- pool + decoder ----
    k_pool<<<FBLOCKS, 512, 0, stream>>>(hwB, batch, pooled);
    k_dec <<<(NGRAPH + 127) / 128, 256, 0, stream>>>(pooled, dec_W1, dec_b1,
                                                     dec_W2, dec_b2, out);
}

// Round 10
// 398.411 us; speedup vs baseline: 1.5323x; 1.1817x over previous
//
#include <hip/hip_runtime.h>

#define NNODES 100000
#define NEDGES 1600000
#define DIM    128
#define OUTD   32
#define NGRAPH 512
#define LDA    136   // padded LDS stride (bf16 elems)

#define NBUCK2  256                          // coarse buckets: dst >> 9
#define BSHIFT  9
#define CAP     12288                        // per-bucket region capacity (mean 8163)
#define EPB2    8192
#define SBLOCKS ((NEDGES + EPB2 - 1) / EPB2) // 196
#define NBUILD  ((NNODES + 511) / 512)       // 196
#define FBLOCKS ((NNODES + 127) / 128)       // 782

using bf16x8 = __attribute__((ext_vector_type(8))) short;
using f32x4  = __attribute__((ext_vector_type(4))) float;
using f32x2  = __attribute__((ext_vector_type(2))) float;

__device__ __forceinline__ short f2bf(float f) {
    unsigned u = __float_as_uint(f);
    unsigned r = (u + 0x7fff + ((u >> 16) & 1)) >> 16;   // RNE
    return (short)r;
}
__device__ __forceinline__ float bf2f(short s) {
    return __uint_as_float(((unsigned)(unsigned short)s) << 16);
}
__device__ __forceinline__ float bf2f_lo(unsigned u) { return __uint_as_float(u << 16); }
__device__ __forceinline__ float bf2f_hi(unsigned u) { return __uint_as_float(u & 0xffff0000u); }

// pack 8 bf16 (LDS chunk) -> 8 fp8 e4m3 bytes
__device__ __forceinline__ uint2 bf8_to_fp8(bf16x8 t) {
    float f0 = bf2f(t[0]), f1 = bf2f(t[1]), f2 = bf2f(t[2]), f3 = bf2f(t[3]);
    float f4 = bf2f(t[4]), f5 = bf2f(t[5]), f6 = bf2f(t[6]), f7 = bf2f(t[7]);
    uint2 o;
    o.x = __builtin_amdgcn_cvt_pk_fp8_f32(f0, f1, 0, false);
    o.x = __builtin_amdgcn_cvt_pk_fp8_f32(f2, f3, o.x, true);
    o.y = __builtin_amdgcn_cvt_pk_fp8_f32(f4, f5, 0, false);
    o.y = __builtin_amdgcn_cvt_pk_fp8_f32(f6, f7, o.y, true);
    return o;
}

// ============================================================
// Prep: weight transposes (bf16 W^T) + cursor init + pooled zero
// WT = [enc_W1, enc_W2, gcn_W0, gcn_W1, gcn_W2]
// ============================================================
__global__ __launch_bounds__(256) void k_prep(
    const float* __restrict__ eW1, const float* __restrict__ eW2,
    const float* __restrict__ gW, short* __restrict__ WT,
    int* __restrict__ gcur, float* __restrict__ pooled)
{
    int idx = blockIdx.x * 256 + threadIdx.x;
    if (idx < 5 * 16384) {
        int mat = idx >> 14, rem = idx & 16383;
        int k = rem >> 7, n = rem & 127;
        const float* src = (mat == 0) ? eW1 : (mat == 1) ? eW2
                                            : (gW + (size_t)(mat - 2) * 16384);
        WT[(size_t)mat * 16384 + n * DIM + k] = f2bf(src[k * DIM + n]);
    }
    if (idx < NBUCK2) gcur[idx] = idx * CAP;
    if (idx < NGRAPH * DIM) pooled[idx] = 0.f;
}

// ============================================================
// CSR build (block-local reservation scatter + per-bucket build)
// ============================================================
__global__ __launch_bounds__(512) void k_scatter(
    const int* __restrict__ src, const int* __restrict__ dst,
    int* __restrict__ gcur, unsigned* __restrict__ tmp)
{
    __shared__ unsigned short rnk[EPB2];
    __shared__ int h[NBUCK2];
    __shared__ int gbase[NBUCK2];
    const int tid  = threadIdx.x;
    const int base = blockIdx.x * EPB2;
    if (tid < NBUCK2) h[tid] = 0;
    __syncthreads();
    #pragma unroll
    for (int it = 0; it < EPB2 / 512; ++it) {
        int e = base + it * 512 + tid;
        if (e < NEDGES) {
            int b = dst[e] >> BSHIFT;
            rnk[it * 512 + tid] = (unsigned short)atomicAdd(&h[b], 1);
        }
    }
    __syncthreads();
    if (tid < NBUCK2 && h[tid] > 0)
        gbase[tid] = atomicAdd(&gcur[tid], h[tid]);
    __syncthreads();
    #pragma unroll
    for (int it = 0; it < EPB2 / 512; ++it) {
        int e = base + it * 512 + tid;
        if (e < NEDGES) {
            int d = dst[e], sv = src[e];
            int b = d >> BSHIFT;
            int pos = gbase[b] + rnk[it * 512 + tid];
            if (pos < (b + 1) * CAP)
                tmp[pos] = (unsigned)sv | ((unsigned)(d & 511) << 17);
        }
    }
}

__global__ __launch_bounds__(512) void k_build(
    const unsigned* __restrict__ tmp, const int* __restrict__ gcur,
    int* __restrict__ row_off, int* __restrict__ cntA,
    float* __restrict__ inv, int* __restrict__ col)
{
    __shared__ int hist[512], sc[512], lcur[512];
    const int tid   = threadIdx.x;
    const int b     = blockIdx.x;
    const int tbase = b * CAP;
    const int cnt_b = min(gcur[b] - tbase, CAP);
    hist[tid] = 0;
    __syncthreads();
    for (int i = tid; i < cnt_b; i += 512)
        atomicAdd(&hist[(tmp[tbase + i] >> 17) & 511], 1);
    __syncthreads();
    const int hv = hist[tid];
    sc[tid] = hv;
    __syncthreads();
    for (int off = 1; off < 512; off <<= 1) {
        int t = (tid >= off) ? sc[tid - off] : 0;
        __syncthreads();
        sc[tid] += t;
        __syncthreads();
    }
    const int start = tbase + sc[tid] - hv;
    lcur[tid] = start;
    const int node = b * 512 + tid;
    if (node < NNODES) {
        row_off[node] = start;
        cntA[node]    = hv;
        inv[node]     = rsqrtf((float)hv + 1.0f);
    }
    __syncthreads();
    for (int i = tid; i < cnt_b; i += 512) {
        unsigned t = tmp[tbase + i];
        int pos = atomicAdd(&lcur[(t >> 17) & 511], 1);
        col[pos] = (int)(t & 0x1FFFFu);
    }
}

// ============================================================
// Fused encoder: x -> relu(xW1+b1) -> relu(..W2+b2) -> (..Wg0)*inv -> g8 (fp8)
// 512 thr / 128 rows; 3 chained MFMA GEMMs, h in LDS.
// ============================================================
__global__ __launch_bounds__(512, 4) void k_enc(
    const float* __restrict__ x, const short* __restrict__ WT,
    const float* __restrict__ b1, const float* __restrict__ b2,
    const float* __restrict__ inv, unsigned char* __restrict__ g8, int M)
{
    __shared__ short As[128 * LDA];
    __shared__ short Bs[128 * LDA];

    const int tid = threadIdx.x;
    const int m0  = blockIdx.x * 128;

    {
        const int row = tid >> 2, ch = (tid & 3) * 32;
        const int gr  = min(m0 + row, M - 1);
        const float4* sp = (const float4*)(x + (size_t)gr * DIM + ch);
        #pragma unroll
        for (int c = 0; c < 4; ++c) {
            float4 f0 = sp[c * 2], f1 = sp[c * 2 + 1];
            short t8[8] = { f2bf(f0.x), f2bf(f0.y), f2bf(f0.z), f2bf(f0.w),
                            f2bf(f1.x), f2bf(f1.y), f2bf(f1.z), f2bf(f1.w) };
            *(bf16x8*)&As[row * LDA + ch + c * 8] = *(bf16x8*)t8;
        }
    }

    const int wave = tid >> 6, lane = tid & 63;
    const int ml = lane & 15, quad = lane >> 4;
    const int w16 = wave * 16;
    const int brow = tid >> 2, bch = (tid & 3) * 32;

    #pragma unroll
    for (int mat = 0; mat < 3; ++mat) {
        if (mat > 0) __syncthreads();
        const short* wt = WT + (size_t)mat * 16384 + brow * DIM + bch;
        #pragma unroll
        for (int c = 0; c < 4; ++c)
            *(bf16x8*)&Bs[brow * LDA + bch + c * 8] = *(const bf16x8*)(wt + c * 8);
        __syncthreads();

        f32x4 acc[8] = {};
        #pragma unroll
        for (int kk = 0; kk < 4; ++kk) {
            const int k0 = kk * 32 + quad * 8;
            bf16x8 a = *(bf16x8*)&As[(w16 + ml) * LDA + k0];
            #pragma unroll
            for (int ni = 0; ni < 8; ++ni) {
                bf16x8 b = *(bf16x8*)&Bs[(ni * 16 + ml) * LDA + k0];
                acc[ni] = __builtin_amdgcn_mfma_f32_16x16x32_bf16(a, b, acc[ni], 0, 0, 0);
            }
        }
        #pragma unroll
        for (int ni = 0; ni < 8; ++ni) {
            const int colc = ni * 16 + ml;
            #pragma unroll
            for (int r = 0; r < 4; ++r) {
                const int rowl = w16 + quad * 4 + r;
                float v = acc[ni][r];
                if (mat == 0)      v = fmaxf(v + b1[colc], 0.f);
                else if (mat == 1) v = fmaxf(v + b2[colc], 0.f);
                else               v *= inv[min(m0 + rowl, M - 1)];
                As[rowl * LDA + colc] = f2bf(v);
            }
        }
    }

    // ---- store g as fp8 (row = 128 B); 4 lanes x 32 B per row ----
    const int srow = w16 + (lane >> 2), sch = (lane & 3) * 32;
    const int grow = m0 + srow;
    if (grow < M) {
        #pragma unroll
        for (int c = 0; c < 4; ++c) {
            bf16x8 t = *(bf16x8*)&As[srow * LDA + sch + c * 8];
            *(uint2*)(g8 + (size_t)grow * DIM + sch + c * 8) = bf8_to_fp8(t);
        }
    }
}

// ============================================================
// gemm_mfma (r7 v1 staging): g8 = fp8((A @ W)*inv[row]), W as bf16 W^T
// ============================================================
__global__ __launch_bounds__(256) void gemm_mfma(
    const short* __restrict__ A, const short* __restrict__ WT,
    const float* __restrict__ inv, unsigned char* __restrict__ g8, int M)
{
    __shared__ short As[128 * LDA];
    __shared__ short Bs[128 * LDA];

    const int tid = threadIdx.x;
    const int m0  = blockIdx.x * 128;

    #pragma unroll
    for (int i = 0; i < 8; ++i) {
        int idx = tid + i * 256;
        int row = idx >> 4, kg = (idx & 15) << 3;
        int r = min(m0 + row, M - 1);
        *(bf16x8*)&As[row * LDA + kg] = *(const bf16x8*)(A + (size_t)r * DIM + kg);
    }
    #pragma unroll
    for (int i = 0; i < 8; ++i) {
        int idx = tid + i * 256;
        int n = idx >> 4, kg = (idx & 15) << 3;
        *(bf16x8*)&Bs[n * LDA + kg] = *(const bf16x8*)(WT + n * DIM + kg);
    }
    __syncthreads();

    const int wave = tid >> 6, lane = tid & 63;
    const int ml = lane & 15, quad = lane >> 4;
    const int w32 = wave * 32;

    f32x4 acc[2][8] = {};
    #pragma unroll
    for (int kk = 0; kk < 4; ++kk) {
        const int k0 = kk * 32 + quad * 8;
        bf16x8 a0 = *(bf16x8*)&As[(w32 + ml) * LDA + k0];
        bf16x8 a1 = *(bf16x8*)&As[(w32 + 16 + ml) * LDA + k0];
        #pragma unroll
        for (int ni = 0; ni < 8; ++ni) {
            bf16x8 b = *(bf16x8*)&Bs[(ni * 16 + ml) * LDA + k0];
            acc[0][ni] = __builtin_amdgcn_mfma_f32_16x16x32_bf16(a0, b, acc[0][ni], 0, 0, 0);
            acc[1][ni] = __builtin_amdgcn_mfma_f32_16x16x32_bf16(a1, b, acc[1][ni], 0, 0, 0);
        }
    }
    __syncthreads();

    short* Cs = As;
    #pragma unroll
    for (int mi = 0; mi < 2; ++mi) {
        #pragma unroll
        for (int ni = 0; ni < 8; ++ni) {
            const int colc = ni * 16 + ml;
            #pragma unroll
            for (int r = 0; r < 4; ++r) {
                const int row = w32 + mi * 16 + quad * 4 + r;
                float v = acc[mi][ni][r] * inv[min(m0 + row, M - 1)];
                Cs[row * LDA + colc] = f2bf(v);
            }
        }
    }
    __syncthreads();
    #pragma unroll
    for (int i = 0; i < 8; ++i) {
        int idx = tid + i * 256;
        int row = idx >> 4, cg = (idx & 15) << 3;
        int gr = m0 + row;
        if (gr < M) {
            bf16x8 t = *(bf16x8*)&Cs[row * LDA + cg];
            *(uint2*)(g8 + (size_t)gr * DIM + cg) = bf8_to_fp8(t);
        }
    }
}

// ============================================================
// Aggregation v3 (fp8 rows): h_out[n] = relu(inv[n]*(g[n]+sum g[src])+b)
// 2 nodes per wave, 32 lanes x 1 dword (4 fp8 feats) per node.
// ============================================================
__global__ __launch_bounds__(512) void k_agg(
    const unsigned* __restrict__ g8, const int* __restrict__ row_off,
    const int* __restrict__ cntA, const int* __restrict__ col,
    const float* __restrict__ inv, const float* __restrict__ bias,
    short* __restrict__ hout)
{
    const int wid  = blockIdx.x * 8 + (threadIdx.x >> 6);
    const int lane = threadIdx.x & 63;
    const int half = lane >> 5;
    const int sl   = lane & 31;
    const int node = wid * 2 + half;
    if (node >= NNODES) return;

    unsigned us = g8[(size_t)node * 32 + sl];
    f32x2 p0 = __builtin_amdgcn_cvt_pk_f32_fp8(us, false);
    f32x2 p1 = __builtin_amdgcn_cvt_pk_f32_fp8(us, true);
    float a0 = p0.x, a1 = p0.y, a2 = p1.x, a3 = p1.y;

    const int s = row_off[node];
    const int e = s + cntA[node];
    int j = s;
    for (; j + 3 < e; j += 4) {
        unsigned v0 = g8[(size_t)col[j]     * 32 + sl];
        unsigned v1 = g8[(size_t)col[j + 1] * 32 + sl];
        unsigned v2 = g8[(size_t)col[j + 2] * 32 + sl];
        unsigned v3 = g8[(size_t)col[j + 3] * 32 + sl];
        f32x2 q;
        q = __builtin_amdgcn_cvt_pk_f32_fp8(v0, false); a0 += q.x; a1 += q.y;
        q = __builtin_amdgcn_cvt_pk_f32_fp8(v0, true);  a2 += q.x; a3 += q.y;
        q = __builtin_amdgcn_cvt_pk_f32_fp8(v1, false); a0 += q.x; a1 += q.y;
        q = __builtin_amdgcn_cvt_pk_f32_fp8(v1, true);  a2 += q.x; a3 += q.y;
        q = __builtin_amdgcn_cvt_pk_f32_fp8(v2, false); a0 += q.x; a1 += q.y;
        q = __builtin_amdgcn_cvt_pk_f32_fp8(v2, true);  a2 += q.x; a3 += q.y;
        q = __builtin_amdgcn_cvt_pk_f32_fp8(v3, false); a0 += q.x; a1 += q.y;
        q = __builtin_amdgcn_cvt_pk_f32_fp8(v3, true);  a2 += q.x; a3 += q.y;
    }
    for (; j < e; ++j) {
        unsigned v = g8[(size_t)col[j] * 32 + sl];
        f32x2 q;
        q = __builtin_amdgcn_cvt_pk_f32_fp8(v, false); a0 += q.x; a1 += q.y;
        q = __builtin_amdgcn_cvt_pk_f32_fp8(v, true);  a2 += q.x; a3 += q.y;
    }
    const float scv = inv[node];
    const float4 bb = ((const float4*)bias)[sl];
    float o0 = fmaxf(fmaf(a0, scv, bb.x), 0.f);
    float o1 = fmaxf(fmaf(a1, scv, bb.y), 0.f);
    float o2 = fmaxf(fmaf(a2, scv, bb.z), 0.f);
    float o3 = fmaxf(fmaf(a3, scv, bb.w), 0.f);
    uint2 o;
    o.x = (unsigned)(unsigned short)f2bf(o0) | ((unsigned)(unsigned short)f2bf(o1) << 16);
    o.y = (unsigned)(unsigned short)f2bf(o2) | ((unsigned)(unsigned short)f2bf(o3) << 16);
    ((uint2*)hout)[(size_t)node * 32 + sl] = o;
}

// ============================================================
// Global add pool: segmented atomic reduction (batch sorted).
// ============================================================
__global__ __launch_bounds__(512) void k_pool(
    const short* __restrict__ h, const int* __restrict__ batch,
    float* __restrict__ pooled)
{
    const int wave = threadIdx.x >> 6, lane = threadIdx.x & 63;
    const int node0 = blockIdx.x * 128 + wave * 16;
    const unsigned* hp = (const unsigned*)h;

    float gx = 0.f, gy = 0.f;
    int cg = -1;
    #pragma unroll 1
    for (int i = 0; i < 16; ++i) {
        const int node = node0 + i;
        if (node >= NNODES) break;
        const int g = batch[node];
        if (g != cg) {
            if (cg >= 0) {
                atomicAdd(pooled + (size_t)cg * DIM + lane * 2,     gx);
                atomicAdd(pooled + (size_t)cg * DIM + lane * 2 + 1, gy);
            }
            cg = g; gx = 0.f; gy = 0.f;
        }
        unsigned v = hp[(size_t)node * 64 + lane];
        gx += bf2f_lo(v);
        gy += bf2f_hi(v);
    }
    if (cg >= 0) {
        atomicAdd(pooled + (size_t)cg * DIM + lane * 2,     gx);
        atomicAdd(pooled + (size_t)cg * DIM + lane * 2 + 1, gy);
    }
}

// ============================================================
// Fused decoder: out = relu(pooled@W1+b1)@W2 + b2
// ============================================================
__global__ __launch_bounds__(256) void k_dec(
    const float* __restrict__ A, const float* __restrict__ W1,
    const float* __restrict__ b1, const float* __restrict__ W2,
    const float* __restrict__ b2, float* __restrict__ out)
{
    __shared__ float As[16][132];
    __shared__ float Bs[16][132];
    __shared__ float T1[128][132];

    const int tid = threadIdx.x;
    const int m0  = blockIdx.x * 128;
    const int tx  = tid & 15;
    const int ty  = tid >> 4;
    const int ar = tid >> 2;
    const int ac = (tid & 3) << 2;
    const int br = tid >> 5;
    const int bc = (tid & 31) << 2;

    float acc[8][8];
    #pragma unroll
    for (int i = 0; i < 8; ++i)
        #pragma unroll
        for (int j = 0; j < 8; ++j) acc[i][j] = 0.f;

    for (int kt = 0; kt < 8; ++kt) {
        const int k0 = kt << 4;
        float4 a0 = *(const float4*)(A + (size_t)(m0 + ar)      * DIM + k0 + ac);
        float4 a1 = *(const float4*)(A + (size_t)(m0 + ar + 64) * DIM + k0 + ac);
        float4 b0 = *(const float4*)(W1 + (size_t)(k0 + br)     * DIM + bc);
        float4 b1v= *(const float4*)(W1 + (size_t)(k0 + br + 8) * DIM + bc);

        __syncthreads();
        As[ac + 0][ar] = a0.x; As[ac + 1][ar] = a0.y;
        As[ac + 2][ar] = a0.z; As[ac + 3][ar] = a0.w;
        As[ac + 0][ar + 64] = a1.x; As[ac + 1][ar + 64] = a1.y;
        As[ac + 2][ar + 64] = a1.z; As[ac + 3][ar + 64] = a1.w;
        *(float4*)&Bs[br][bc]     = b0;
        *(float4*)&Bs[br + 8][bc] = b1v;
        __syncthreads();

        #pragma unroll
        for (int kk = 0; kk < 16; ++kk) {
            float4 fa0 = *(const float4*)&As[kk][ty * 8];
            float4 fa1 = *(const float4*)&As[kk][ty * 8 + 4];
            float4 fb0 = *(const float4*)&Bs[kk][tx * 8];
            float4 fb1 = *(const float4*)&Bs[kk][tx * 8 + 4];
            float av[8] = {fa0.x, fa0.y, fa0.z, fa0.w, fa1.x, fa1.y, fa1.z, fa1.w};
            float bv[8] = {fb0.x, fb0.y, fb0.z, fb0.w, fb1.x, fb1.y, fb1.z, fb1.w};
            #pragma unroll
            for (int i = 0; i < 8; ++i)
                #pragma unroll
                for (int j = 0; j < 8; ++j)
                    acc[i][j] = fmaf(av[i], bv[j], acc[i][j]);
        }
    }

    float4 bb0 = *(const float4*)(b1 + tx * 8);
    float4 bb1 = *(const float4*)(b1 + tx * 8 + 4);
    float bcol[8] = {bb0.x, bb0.y, bb0.z, bb0.w, bb1.x, bb1.y, bb1.z, bb1.w};

    #pragma unroll
    for (int i = 0; i < 8; ++i) {
        const int rl = ty * 8 + i;
        #pragma unroll
        for (int j = 0; j < 8; ++j)
            T1[rl][tx * 8 + j] = fmaxf(acc[i][j] + bcol[j], 0.f);
    }
    __syncthreads();

    const int c  = tid & 31;
    const int rg = tid >> 5;
    #pragma unroll 1
    for (int j = 0; j < 16; ++j) {
        const int r = rg + j * 8;
        float a2 = b2[c];
        #pragma unroll 8
        for (int k = 0; k < DIM; ++k)
            a2 = fmaf(T1[r][k], W2[(size_t)k * OUTD + c], a2);
        out[(size_t)(m0 + r) * OUTD + c] = a2;
    }
}

// ============================================================
extern "C" void kernel_launch(void* const* d_in, const int* in_sizes, int n_in,
                              void* d_out, int out_size, void* d_ws, size_t ws_size,
                              hipStream_t stream)
{
    const float* x      = (const float*)d_in[0];
    const int*   ei     = (const int*)d_in[1];
    const int*   batch  = (const int*)d_in[2];
    const float* enc_W1 = (const float*)d_in[3];
    const float* enc_b1 = (const float*)d_in[4];
    const float* enc_W2 = (const float*)d_in[5];
    const float* enc_b2 = (const float*)d_in[6];
    const float* gcn_W  = (const float*)d_in[7];
    const float* gcn_b  = (const float*)d_in[8];
    const float* dec_W1 = (const float*)d_in[9];
    const float* dec_b1 = (const float*)d_in[10];
    const float* dec_W2 = (const float*)d_in[11];
    const float* dec_b2 = (const float*)d_in[12];
    float* out = (float*)d_out;

    const int* src = ei;
    const int* dst = ei + NEDGES;

    char* p = (char*)d_ws;
    auto alloc = [&](size_t bytes) -> void* {
        void* r = (void*)p;
        p += (bytes + 255) & ~(size_t)255;
        return r;
    };
    short*         hw     = (short*)        alloc((size_t)NNODES * DIM * sizeof(short));
    unsigned char* g8     = (unsigned char*)alloc((size_t)NNODES * DIM);
    float*         inv    = (float*)        alloc((size_t)NNODES * sizeof(float));
    int*           row_off= (int*)          alloc((size_t)NNODES * sizeof(int));
    int*           cntA   = (int*)          alloc((size_t)NNODES * sizeof(int));
    int*           col    = (int*)          alloc((size_t)NBUCK2 * CAP * sizeof(int));
    unsigned*      tmp    = (unsigned*)     alloc((size_t)NBUCK2 * CAP * sizeof(unsigned));
    int*           gcur   = (int*)          alloc((size_t)NBUCK2 * sizeof(int));
    short*         WT     = (short*)        alloc((size_t)5 * DIM * DIM * sizeof(short));
    float*         pooled = (float*)        alloc((size_t)NGRAPH * DIM * sizeof(float));

    // ---- prep + CSR build ----
    k_prep   <<<(5 * 16384 + 255) / 256, 256, 0, stream>>>(enc_W1, enc_W2, gcn_W,
                                                           WT, gcur, pooled);
    k_scatter<<<SBLOCKS, 512, 0, stream>>>(src, dst, gcur, tmp);
    k_build  <<<NBUILD, 512, 0, stream>>>(tmp, gcur, row_off, cntA, inv, col);

    // ---- fused encoder: x -> g0 (fp8) ----
    k_enc<<<FBLOCKS, 512, 0, stream>>>(x, WT, enc_b1, enc_b2, inv, g8, NNODES);

    // ---- GCN layers: agg (g8 -> hw bf16) then gemm (hw -> g8 fp8) ----
    const int aggBlocks = (NNODES + 15) / 16;
    k_agg<<<aggBlocks, 512, 0, stream>>>((const unsigned*)g8, row_off, cntA, col,
                                         inv, gcn_b, hw);
    gemm_mfma<<<FBLOCKS, 256, 0, stream>>>(hw, WT + 3 * 16384, inv, g8, NNODES);
    k_agg<<<aggBlocks, 512, 0, stream>>>((const unsigned*)g8, row_off, cntA, col,
                                         inv, gcn_b + 128, hw);
    gemm_mfma<<<FBLOCKS, 256, 0, stream>>>(hw, WT + 4 * 16384, inv, g8, NNODES);
    k_agg<<<aggBlocks, 512, 0, stream>>>((const unsigned*)g8, row_off, cntA, col,
                                         inv, gcn_b + 256, hw);

    // ---- pool + decoder ----
    k_pool<<<FBLOCKS, 512, 0, stream>>>(hw, batch, pooled);
    k_dec <<<(NGRAPH + 127) / 128, 256, 0, stream>>>(pooled, dec_W1, dec_b1,
                                                     dec_W2, dec_b2, out);
}

// Round 11
// 341.982 us; speedup vs baseline: 1.7851x; 1.1650x over previous
//
#include <hip/hip_runtime.h>

#define NNODES 100000
#define NEDGES 1600000
#define DIM    128
#define OUTD   32
#define NGRAPH 512
#define LDA    136   // padded LDS stride (bf16 elems)

#define NBUCK2  256                          // coarse buckets: dst >> 9
#define BSHIFT  9
#define CAP     12288                        // per-bucket region capacity (mean 8163)
#define EPB2    8192
#define SBLOCKS ((NEDGES + EPB2 - 1) / EPB2) // 196
#define NBUILD  ((NNODES + 511) / 512)       // 196
#define FBLOCKS ((NNODES + 127) / 128)       // 782

using bf16x8 = __attribute__((ext_vector_type(8))) short;
using f32x4  = __attribute__((ext_vector_type(4))) float;
using f32x2  = __attribute__((ext_vector_type(2))) float;

__device__ __forceinline__ short f2bf(float f) {
    unsigned u = __float_as_uint(f);
    unsigned r = (u + 0x7fff + ((u >> 16) & 1)) >> 16;   // RNE
    return (short)r;
}
__device__ __forceinline__ float bf2f(short s) {
    return __uint_as_float(((unsigned)(unsigned short)s) << 16);
}
__device__ __forceinline__ float bf2f_lo(unsigned u) { return __uint_as_float(u << 16); }
__device__ __forceinline__ float bf2f_hi(unsigned u) { return __uint_as_float(u & 0xffff0000u); }

// pack 8 bf16 (LDS chunk) -> 8 fp8 e4m3 bytes
__device__ __forceinline__ uint2 bf8_to_fp8(bf16x8 t) {
    float f0 = bf2f(t[0]), f1 = bf2f(t[1]), f2 = bf2f(t[2]), f3 = bf2f(t[3]);
    float f4 = bf2f(t[4]), f5 = bf2f(t[5]), f6 = bf2f(t[6]), f7 = bf2f(t[7]);
    uint2 o;
    o.x = __builtin_amdgcn_cvt_pk_fp8_f32(f0, f1, 0, false);
    o.x = __builtin_amdgcn_cvt_pk_fp8_f32(f2, f3, o.x, true);
    o.y = __builtin_amdgcn_cvt_pk_fp8_f32(f4, f5, 0, false);
    o.y = __builtin_amdgcn_cvt_pk_fp8_f32(f6, f7, o.y, true);
    return o;
}

// ============================================================
// Prep: weight transposes (bf16 W^T) + cursor init + pooled zero
// ============================================================
__global__ __launch_bounds__(256) void k_prep(
    const float* __restrict__ eW1, const float* __restrict__ eW2,
    const float* __restrict__ gW, short* __restrict__ WT,
    int* __restrict__ gcur, float* __restrict__ pooled)
{
    int idx = blockIdx.x * 256 + threadIdx.x;
    if (idx < 5 * 16384) {
        int mat = idx >> 14, rem = idx & 16383;
        int k = rem >> 7, n = rem & 127;
        const float* src = (mat == 0) ? eW1 : (mat == 1) ? eW2
                                            : (gW + (size_t)(mat - 2) * 16384);
        WT[(size_t)mat * 16384 + n * DIM + k] = f2bf(src[k * DIM + n]);
    }
    if (idx < NBUCK2) gcur[idx] = idx * CAP;
    if (idx < NGRAPH * DIM) pooled[idx] = 0.f;
}

// ============================================================
// CSR build (block-local reservation scatter + per-bucket build)
// ============================================================
__global__ __launch_bounds__(512) void k_scatter(
    const int* __restrict__ src, const int* __restrict__ dst,
    int* __restrict__ gcur, unsigned* __restrict__ tmp)
{
    __shared__ unsigned short rnk[EPB2];
    __shared__ int h[NBUCK2];
    __shared__ int gbase[NBUCK2];
    const int tid  = threadIdx.x;
    const int base = blockIdx.x * EPB2;
    if (tid < NBUCK2) h[tid] = 0;
    __syncthreads();
    #pragma unroll
    for (int it = 0; it < EPB2 / 512; ++it) {
        int e = base + it * 512 + tid;
        if (e < NEDGES) {
            int b = dst[e] >> BSHIFT;
            rnk[it * 512 + tid] = (unsigned short)atomicAdd(&h[b], 1);
        }
    }
    __syncthreads();
    if (tid < NBUCK2 && h[tid] > 0)
        gbase[tid] = atomicAdd(&gcur[tid], h[tid]);
    __syncthreads();
    #pragma unroll
    for (int it = 0; it < EPB2 / 512; ++it) {
        int e = base + it * 512 + tid;
        if (e < NEDGES) {
            int d = dst[e], sv = src[e];
            int b = d >> BSHIFT;
            int pos = gbase[b] + rnk[it * 512 + tid];
            if (pos < (b + 1) * CAP)
                tmp[pos] = (unsigned)sv | ((unsigned)(d & 511) << 17);
        }
    }
}

__global__ __launch_bounds__(512) void k_build(
    const unsigned* __restrict__ tmp, const int* __restrict__ gcur,
    int* __restrict__ row_off, int* __restrict__ cntA,
    float* __restrict__ inv, int* __restrict__ col)
{
    __shared__ int hist[512], sc[512], lcur[512];
    const int tid   = threadIdx.x;
    const int b     = blockIdx.x;
    const int tbase = b * CAP;
    const int cnt_b = min(gcur[b] - tbase, CAP);
    hist[tid] = 0;
    __syncthreads();
    for (int i = tid; i < cnt_b; i += 512)
        atomicAdd(&hist[(tmp[tbase + i] >> 17) & 511], 1);
    __syncthreads();
    const int hv = hist[tid];
    sc[tid] = hv;
    __syncthreads();
    for (int off = 1; off < 512; off <<= 1) {
        int t = (tid >= off) ? sc[tid - off] : 0;
        __syncthreads();
        sc[tid] += t;
        __syncthreads();
    }
    const int start = tbase + sc[tid] - hv;
    lcur[tid] = start;
    const int node = b * 512 + tid;
    if (node < NNODES) {
        row_off[node] = start;
        cntA[node]    = hv;
        inv[node]     = rsqrtf((float)hv + 1.0f);
    }
    __syncthreads();
    for (int i = tid; i < cnt_b; i += 512) {
        unsigned t = tmp[tbase + i];
        int pos = atomicAdd(&lcur[(t >> 17) & 511], 1);
        col[pos] = (int)(t & 0x1FFFFu);
    }
}

// ============================================================
// Fused encoder: x -> relu(xW1+b1) -> relu(..W2+b2) -> (..Wg0)*inv -> g8 (fp8)
// ============================================================
__global__ __launch_bounds__(512, 4) void k_enc(
    const float* __restrict__ x, const short* __restrict__ WT,
    const float* __restrict__ b1, const float* __restrict__ b2,
    const float* __restrict__ inv, unsigned char* __restrict__ g8, int M)
{
    __shared__ short As[128 * LDA];
    __shared__ short Bs[128 * LDA];

    const int tid = threadIdx.x;
    const int m0  = blockIdx.x * 128;

    {
        const int row = tid >> 2, ch = (tid & 3) * 32;
        const int gr  = min(m0 + row, M - 1);
        const float4* sp = (const float4*)(x + (size_t)gr * DIM + ch);
        #pragma unroll
        for (int c = 0; c < 4; ++c) {
            float4 f0 = sp[c * 2], f1 = sp[c * 2 + 1];
            short t8[8] = { f2bf(f0.x), f2bf(f0.y), f2bf(f0.z), f2bf(f0.w),
                            f2bf(f1.x), f2bf(f1.y), f2bf(f1.z), f2bf(f1.w) };
            *(bf16x8*)&As[row * LDA + ch + c * 8] = *(bf16x8*)t8;
        }
    }

    const int wave = tid >> 6, lane = tid & 63;
    const int ml = lane & 15, quad = lane >> 4;
    const int w16 = wave * 16;
    const int brow = tid >> 2, bch = (tid & 3) * 32;

    #pragma unroll
    for (int mat = 0; mat < 3; ++mat) {
        if (mat > 0) __syncthreads();
        const short* wt = WT + (size_t)mat * 16384 + brow * DIM + bch;
        #pragma unroll
        for (int c = 0; c < 4; ++c)
            *(bf16x8*)&Bs[brow * LDA + bch + c * 8] = *(const bf16x8*)(wt + c * 8);
        __syncthreads();

        f32x4 acc[8] = {};
        #pragma unroll
        for (int kk = 0; kk < 4; ++kk) {
            const int k0 = kk * 32 + quad * 8;
            bf16x8 a = *(bf16x8*)&As[(w16 + ml) * LDA + k0];
            #pragma unroll
            for (int ni = 0; ni < 8; ++ni) {
                bf16x8 b = *(bf16x8*)&Bs[(ni * 16 + ml) * LDA + k0];
                acc[ni] = __builtin_amdgcn_mfma_f32_16x16x32_bf16(a, b, acc[ni], 0, 0, 0);
            }
        }
        #pragma unroll
        for (int ni = 0; ni < 8; ++ni) {
            const int colc = ni * 16 + ml;
            #pragma unroll
            for (int r = 0; r < 4; ++r) {
                const int rowl = w16 + quad * 4 + r;
                float v = acc[ni][r];
                if (mat == 0)      v = fmaxf(v + b1[colc], 0.f);
                else if (mat == 1) v = fmaxf(v + b2[colc], 0.f);
                else               v *= inv[min(m0 + rowl, M - 1)];
                As[rowl * LDA + colc] = f2bf(v);
            }
        }
    }

    const int srow = w16 + (lane >> 2), sch = (lane & 3) * 32;
    const int grow = m0 + srow;
    if (grow < M) {
        #pragma unroll
        for (int c = 0; c < 4; ++c) {
            bf16x8 t = *(bf16x8*)&As[srow * LDA + sch + c * 8];
            *(uint2*)(g8 + (size_t)grow * DIM + sch + c * 8) = bf8_to_fp8(t);
        }
    }
}

// ============================================================
// gemm_mfma: g8 = fp8((A @ W)*inv[row]), W as bf16 W^T
// ============================================================
__global__ __launch_bounds__(256) void gemm_mfma(
    const short* __restrict__ A, const short* __restrict__ WT,
    const float* __restrict__ inv, unsigned char* __restrict__ g8, int M)
{
    __shared__ short As[128 * LDA];
    __shared__ short Bs[128 * LDA];

    const int tid = threadIdx.x;
    const int m0  = blockIdx.x * 128;

    #pragma unroll
    for (int i = 0; i < 8; ++i) {
        int idx = tid + i * 256;
        int row = idx >> 4, kg = (idx & 15) << 3;
        int r = min(m0 + row, M - 1);
        *(bf16x8*)&As[row * LDA + kg] = *(const bf16x8*)(A + (size_t)r * DIM + kg);
    }
    #pragma unroll
    for (int i = 0; i < 8; ++i) {
        int idx = tid + i * 256;
        int n = idx >> 4, kg = (idx & 15) << 3;
        *(bf16x8*)&Bs[n * LDA + kg] = *(const bf16x8*)(WT + n * DIM + kg);
    }
    __syncthreads();

    const int wave = tid >> 6, lane = tid & 63;
    const int ml = lane & 15, quad = lane >> 4;
    const int w32 = wave * 32;

    f32x4 acc[2][8] = {};
    #pragma unroll
    for (int kk = 0; kk < 4; ++kk) {
        const int k0 = kk * 32 + quad * 8;
        bf16x8 a0 = *(bf16x8*)&As[(w32 + ml) * LDA + k0];
        bf16x8 a1 = *(bf16x8*)&As[(w32 + 16 + ml) * LDA + k0];
        #pragma unroll
        for (int ni = 0; ni < 8; ++ni) {
            bf16x8 b = *(bf16x8*)&Bs[(ni * 16 + ml) * LDA + k0];
            acc[0][ni] = __builtin_amdgcn_mfma_f32_16x16x32_bf16(a0, b, acc[0][ni], 0, 0, 0);
            acc[1][ni] = __builtin_amdgcn_mfma_f32_16x16x32_bf16(a1, b, acc[1][ni], 0, 0, 0);
        }
    }
    __syncthreads();

    short* Cs = As;
    #pragma unroll
    for (int mi = 0; mi < 2; ++mi) {
        #pragma unroll
        for (int ni = 0; ni < 8; ++ni) {
            const int colc = ni * 16 + ml;
            #pragma unroll
            for (int r = 0; r < 4; ++r) {
                const int row = w32 + mi * 16 + quad * 4 + r;
                float v = acc[mi][ni][r] * inv[min(m0 + row, M - 1)];
                Cs[row * LDA + colc] = f2bf(v);
            }
        }
    }
    __syncthreads();
    #pragma unroll
    for (int i = 0; i < 8; ++i) {
        int idx = tid + i * 256;
        int row = idx >> 4, cg = (idx & 15) << 3;
        int gr = m0 + row;
        if (gr < M) {
            bf16x8 t = *(bf16x8*)&Cs[row * LDA + cg];
            *(uint2*)(g8 + (size_t)gr * DIM + cg) = bf8_to_fp8(t);
        }
    }
}

// ============================================================
// Aggregation v4 (fp8 rows): 4 nodes per wave, 16 lanes x uint2 (8B/row seg).
// Each load instruction fetches 4 x 128B rows.
// ============================================================
__global__ __launch_bounds__(512) void k_agg(
    const unsigned char* __restrict__ g8v, const int* __restrict__ row_off,
    const int* __restrict__ cntA, const int* __restrict__ col,
    const float* __restrict__ inv, const float* __restrict__ bias,
    short* __restrict__ hout)
{
    const int wid  = blockIdx.x * 8 + (threadIdx.x >> 6);
    const int lane = threadIdx.x & 63;
    const int q    = lane >> 4;      // quarter-wave 0..3
    const int sl   = lane & 15;      // sub-lane 0..15
    const int node = wid * 4 + q;
    if (node >= NNODES) return;

    const uint2* hp = (const uint2*)g8v;   // row = 16 x uint2 = 128 B
    uint2 us = hp[(size_t)node * 16 + sl];
    f32x2 p;
    float a0, a1, a2, a3, a4, a5, a6, a7;
    p = __builtin_amdgcn_cvt_pk_f32_fp8(us.x, false); a0 = p.x; a1 = p.y;
    p = __builtin_amdgcn_cvt_pk_f32_fp8(us.x, true);  a2 = p.x; a3 = p.y;
    p = __builtin_amdgcn_cvt_pk_f32_fp8(us.y, false); a4 = p.x; a5 = p.y;
    p = __builtin_amdgcn_cvt_pk_f32_fp8(us.y, true);  a6 = p.x; a7 = p.y;

    const int s = row_off[node];
    const int e = s + cntA[node];
    int j = s;
    for (; j + 3 < e; j += 4) {
        uint2 v0 = hp[(size_t)col[j]     * 16 + sl];
        uint2 v1 = hp[(size_t)col[j + 1] * 16 + sl];
        uint2 v2 = hp[(size_t)col[j + 2] * 16 + sl];
        uint2 v3 = hp[(size_t)col[j + 3] * 16 + sl];
        #define ACC8(v) \
            p = __builtin_amdgcn_cvt_pk_f32_fp8(v.x, false); a0 += p.x; a1 += p.y; \
            p = __builtin_amdgcn_cvt_pk_f32_fp8(v.x, true);  a2 += p.x; a3 += p.y; \
            p = __builtin_amdgcn_cvt_pk_f32_fp8(v.y, false); a4 += p.x; a5 += p.y; \
            p = __builtin_amdgcn_cvt_pk_f32_fp8(v.y, true);  a6 += p.x; a7 += p.y;
        ACC8(v0) ACC8(v1) ACC8(v2) ACC8(v3)
    }
    for (; j < e; ++j) {
        uint2 v = hp[(size_t)col[j] * 16 + sl];
        ACC8(v)
        #undef ACC8
    }
    const float scv = inv[node];
    const float4 bb0 = ((const float4*)bias)[sl * 2];
    const float4 bb1 = ((const float4*)bias)[sl * 2 + 1];
    short o[8];
    o[0] = f2bf(fmaxf(fmaf(a0, scv, bb0.x), 0.f));
    o[1] = f2bf(fmaxf(fmaf(a1, scv, bb0.y), 0.f));
    o[2] = f2bf(fmaxf(fmaf(a2, scv, bb0.z), 0.f));
    o[3] = f2bf(fmaxf(fmaf(a3, scv, bb0.w), 0.f));
    o[4] = f2bf(fmaxf(fmaf(a4, scv, bb1.x), 0.f));
    o[5] = f2bf(fmaxf(fmaf(a5, scv, bb1.y), 0.f));
    o[6] = f2bf(fmaxf(fmaf(a6, scv, bb1.z), 0.f));
    o[7] = f2bf(fmaxf(fmaf(a7, scv, bb1.w), 0.f));
    ((bf16x8*)hout)[(size_t)node * 16 + sl] = *(bf16x8*)o;
}

// ============================================================
// Global add pool: segmented atomic reduction (batch sorted).
// ============================================================
__global__ __launch_bounds__(512) void k_pool(
    const short* __restrict__ h, const int* __restrict__ batch,
    float* __restrict__ pooled)
{
    const int wave = threadIdx.x >> 6, lane = threadIdx.x & 63;
    const int node0 = blockIdx.x * 128 + wave * 16;
    const unsigned* hp = (const unsigned*)h;

    float gx = 0.f, gy = 0.f;
    int cg = -1;
    #pragma unroll 1
    for (int i = 0; i < 16; ++i) {
        const int node = node0 + i;
        if (node >= NNODES) break;
        const int g = batch[node];
        if (g != cg) {
            if (cg >= 0) {
                atomicAdd(pooled + (size_t)cg * DIM + lane * 2,     gx);
                atomicAdd(pooled + (size_t)cg * DIM + lane * 2 + 1, gy);
            }
            cg = g; gx = 0.f; gy = 0.f;
        }
        unsigned v = hp[(size_t)node * 64 + lane];
        gx += bf2f_lo(v);
        gy += bf2f_hi(v);
    }
    if (cg >= 0) {
        atomicAdd(pooled + (size_t)cg * DIM + lane * 2,     gx);
        atomicAdd(pooled + (size_t)cg * DIM + lane * 2 + 1, gy);
    }
}

// ============================================================
// Decoder v2: one wave per graph (64 blocks x 8 waves).
// out[g] = relu(pooled[g]@W1+b1)@W2+b2
// ============================================================
__global__ __launch_bounds__(512) void k_dec(
    const float* __restrict__ pooled, const float* __restrict__ W1,
    const float* __restrict__ b1, const float* __restrict__ W2,
    const float* __restrict__ b2, float* __restrict__ out)
{
    __shared__ float pbuf[8][128];
    __shared__ float tbuf[8][128];
    const int wave = threadIdx.x >> 6, lane = threadIdx.x & 63;
    const int g = blockIdx.x * 8 + wave;

    float2 pv = *(const float2*)(pooled + (size_t)g * DIM + lane * 2);
    pbuf[wave][lane * 2]     = pv.x;
    pbuf[wave][lane * 2 + 1] = pv.y;
    __syncthreads();

    // stage 1: t1 = relu(p @ W1 + b1); lane covers cols 2*lane, 2*lane+1
    float t0 = 0.f, t1 = 0.f;
    #pragma unroll 8
    for (int k = 0; k < DIM; ++k) {
        float pk = pbuf[wave][k];
        float2 w = *(const float2*)(W1 + (size_t)k * DIM + lane * 2);
        t0 = fmaf(pk, w.x, t0);
        t1 = fmaf(pk, w.y, t1);
    }
    tbuf[wave][lane * 2]     = fmaxf(t0 + b1[lane * 2],     0.f);
    tbuf[wave][lane * 2 + 1] = fmaxf(t1 + b1[lane * 2 + 1], 0.f);
    __syncthreads();

    // stage 2: lane = c + 32*h; half-wave h covers k in [64h, 64h+64)
    const int c = lane & 31, hh = lane >> 5;
    float part = 0.f;
    #pragma unroll 8
    for (int kk = 0; kk < 64; ++kk) {
        int k = hh * 64 + kk;
        part = fmaf(tbuf[wave][k], W2[(size_t)k * OUTD + c], part);
    }
    float other = __shfl_xor(part, 32, 64);
    if (hh == 0)
        out[(size_t)g * OUTD + c] = part + other + b2[c];
}

// ============================================================
extern "C" void kernel_launch(void* const* d_in, const int* in_sizes, int n_in,
                              void* d_out, int out_size, void* d_ws, size_t ws_size,
                              hipStream_t stream)
{
    const float* x      = (const float*)d_in[0];
    const int*   ei     = (const int*)d_in[1];
    const int*   batch  = (const int*)d_in[2];
    const float* enc_W1 = (const float*)d_in[3];
    const float* enc_b1 = (const float*)d_in[4];
    const float* enc_W2 = (const float*)d_in[5];
    const float* enc_b2 = (const float*)d_in[6];
    const float* gcn_W  = (const float*)d_in[7];
    const float* gcn_b  = (const float*)d_in[8];
    const float* dec_W1 = (const float*)d_in[9];
    const float* dec_b1 = (const float*)d_in[10];
    const float* dec_W2 = (const float*)d_in[11];
    const float* dec_b2 = (const float*)d_in[12];
    float* out = (float*)d_out;

    const int* src = ei;
    const int* dst = ei + NEDGES;

    char* p = (char*)d_ws;
    auto alloc = [&](size_t bytes) -> void* {
        void* r = (void*)p;
        p += (bytes + 255) & ~(size_t)255;
        return r;
    };
    short*         hw     = (short*)        alloc((size_t)NNODES * DIM * sizeof(short));
    unsigned char* g8     = (unsigned char*)alloc((size_t)NNODES * DIM);
    float*         inv    = (float*)        alloc((size_t)NNODES * sizeof(float));
    int*           row_off= (int*)          alloc((size_t)NNODES * sizeof(int));
    int*           cntA   = (int*)          alloc((size_t)NNODES * sizeof(int));
    int*           col    = (int*)          alloc((size_t)NBUCK2 * CAP * sizeof(int));
    unsigned*      tmp    = (unsigned*)     alloc((size_t)NBUCK2 * CAP * sizeof(unsigned));
    int*           gcur   = (int*)          alloc((size_t)NBUCK2 * sizeof(int));
    short*         WT     = (short*)        alloc((size_t)5 * DIM * DIM * sizeof(short));
    float*         pooled = (float*)        alloc((size_t)NGRAPH * DIM * sizeof(float));

    // ---- prep + CSR build ----
    k_prep   <<<(5 * 16384 + 255) / 256, 256, 0, stream>>>(enc_W1, enc_W2, gcn_W,
                                                           WT, gcur, pooled);
    k_scatter<<<SBLOCKS, 512, 0, stream>>>(src, dst, gcur, tmp);
    k_build  <<<NBUILD, 512, 0, stream>>>(tmp, gcur, row_off, cntA, inv, col);

    // ---- fused encoder: x -> g0 (fp8) ----
    k_enc<<<FBLOCKS, 512, 0, stream>>>(x, WT, enc_b1, enc_b2, inv, g8, NNODES);

    // ---- GCN layers: agg (g8 -> hw bf16) then gemm (hw -> g8 fp8) ----
    const int aggBlocks = (NNODES + 31) / 32;   // 4 nodes/wave, 8 waves/block
    k_agg<<<aggBlocks, 512, 0, stream>>>(g8, row_off, cntA, col, inv, gcn_b, hw);
    gemm_mfma<<<FBLOCKS, 256, 0, stream>>>(hw, WT + 3 * 16384, inv, g8, NNODES);
    k_agg<<<aggBlocks, 512, 0, stream>>>(g8, row_off, cntA, col, inv, gcn_b + 128, hw);
    gemm_mfma<<<FBLOCKS, 256, 0, stream>>>(hw, WT + 4 * 16384, inv, g8, NNODES);
    k_agg<<<aggBlocks, 512, 0, stream>>>(g8, row_off, cntA, col, inv, gcn_b + 256, hw);

    // ---- pool + decoder ----
    k_pool<<<FBLOCKS, 512, 0, stream>>>(hw, batch, pooled);
    k_dec <<<NGRAPH / 8, 512, 0, stream>>>(pooled, dec_W1, dec_b1,
                                           dec_W2, dec_b2, out);
}

// Round 13
// 335.048 us; speedup vs baseline: 1.8221x; 1.0207x over previous
//
#include <hip/hip_runtime.h>

#define NNODES 100000
#define NEDGES 1600000
#define DIM    128
#define OUTD   32
#define NGRAPH 512
#define LDA    136   // padded LDS stride (bf16 elems)

#define NBUCK2  256                          // coarse buckets: dst >> 9
#define BSHIFT  9
#define CAP     12288                        // per-bucket region capacity (mean 8163)
#define EPB2    8192
#define SBLOCKS ((NEDGES + EPB2 - 1) / EPB2) // 196
#define NBUILD  ((NNODES + 511) / 512)       // 196
#define FBLOCKS ((NNODES + 127) / 128)       // 782

using bf16x8 = __attribute__((ext_vector_type(8))) short;
using f32x4  = __attribute__((ext_vector_type(4))) float;
using f32x2  = __attribute__((ext_vector_type(2))) float;

__device__ __forceinline__ short f2bf(float f) {
    unsigned u = __float_as_uint(f);
    unsigned r = (u + 0x7fff + ((u >> 16) & 1)) >> 16;   // RNE
    return (short)r;
}
__device__ __forceinline__ float bf2f(short s) {
    return __uint_as_float(((unsigned)(unsigned short)s) << 16);
}
__device__ __forceinline__ float bf2f_lo(unsigned u) { return __uint_as_float(u << 16); }
__device__ __forceinline__ float bf2f_hi(unsigned u) { return __uint_as_float(u & 0xffff0000u); }

// pack 8 bf16 -> 8 fp8 e4m3 bytes
__device__ __forceinline__ uint2 bf8_to_fp8(bf16x8 t) {
    float f0 = bf2f(t[0]), f1 = bf2f(t[1]), f2 = bf2f(t[2]), f3 = bf2f(t[3]);
    float f4 = bf2f(t[4]), f5 = bf2f(t[5]), f6 = bf2f(t[6]), f7 = bf2f(t[7]);
    uint2 o;
    o.x = __builtin_amdgcn_cvt_pk_fp8_f32(f0, f1, 0, false);
    o.x = __builtin_amdgcn_cvt_pk_fp8_f32(f2, f3, o.x, true);
    o.y = __builtin_amdgcn_cvt_pk_fp8_f32(f4, f5, 0, false);
    o.y = __builtin_amdgcn_cvt_pk_fp8_f32(f6, f7, o.y, true);
    return o;
}

// ============================================================
// Prep: weight transposes (bf16 W^T) + cursor init + pooled zero
// ============================================================
__global__ __launch_bounds__(256) void k_prep(
    const float* __restrict__ eW1, const float* __restrict__ eW2,
    const float* __restrict__ gW, short* __restrict__ WT,
    int* __restrict__ gcur, float* __restrict__ pooled)
{
    int idx = blockIdx.x * 256 + threadIdx.x;
    if (idx < 5 * 16384) {
        int mat = idx >> 14, rem = idx & 16383;
        int k = rem >> 7, n = rem & 127;
        const float* src = (mat == 0) ? eW1 : (mat == 1) ? eW2
                                            : (gW + (size_t)(mat - 2) * 16384);
        WT[(size_t)mat * 16384 + n * DIM + k] = f2bf(src[k * DIM + n]);
    }
    if (idx < NBUCK2) gcur[idx] = idx * CAP;
    if (idx < NGRAPH * DIM) pooled[idx] = 0.f;
}

// ============================================================
// CSR build (block-local reservation scatter + per-bucket build)
// ============================================================
__global__ __launch_bounds__(512) void k_scatter(
    const int* __restrict__ src, const int* __restrict__ dst,
    int* __restrict__ gcur, unsigned* __restrict__ tmp)
{
    __shared__ unsigned short rnk[EPB2];
    __shared__ int h[NBUCK2];
    __shared__ int gbase[NBUCK2];
    const int tid  = threadIdx.x;
    const int base = blockIdx.x * EPB2;
    if (tid < NBUCK2) h[tid] = 0;
    __syncthreads();
    #pragma unroll
    for (int it = 0; it < EPB2 / 512; ++it) {
        int e = base + it * 512 + tid;
        if (e < NEDGES) {
            int b = dst[e] >> BSHIFT;
            rnk[it * 512 + tid] = (unsigned short)atomicAdd(&h[b], 1);
        }
    }
    __syncthreads();
    if (tid < NBUCK2 && h[tid] > 0)
        gbase[tid] = atomicAdd(&gcur[tid], h[tid]);
    __syncthreads();
    #pragma unroll
    for (int it = 0; it < EPB2 / 512; ++it) {
        int e = base + it * 512 + tid;
        if (e < NEDGES) {
            int d = dst[e], sv = src[e];
            int b = d >> BSHIFT;
            int pos = gbase[b] + rnk[it * 512 + tid];
            if (pos < (b + 1) * CAP)
                tmp[pos] = (unsigned)sv | ((unsigned)(d & 511) << 17);
        }
    }
}

__global__ __launch_bounds__(512) void k_build(
    const unsigned* __restrict__ tmp, const int* __restrict__ gcur,
    int* __restrict__ row_off, int* __restrict__ cntA,
    float* __restrict__ inv, int* __restrict__ col)
{
    __shared__ int hist[512], sc[512], lcur[512];
    const int tid   = threadIdx.x;
    const int b     = blockIdx.x;
    const int tbase = b * CAP;
    const int cnt_b = min(gcur[b] - tbase, CAP);
    hist[tid] = 0;
    __syncthreads();
    for (int i = tid; i < cnt_b; i += 512)
        atomicAdd(&hist[(tmp[tbase + i] >> 17) & 511], 1);
    __syncthreads();
    const int hv = hist[tid];
    sc[tid] = hv;
    __syncthreads();
    for (int off = 1; off < 512; off <<= 1) {
        int t = (tid >= off) ? sc[tid - off] : 0;
        __syncthreads();
        sc[tid] += t;
        __syncthreads();
    }
    const int start = tbase + sc[tid] - hv;
    lcur[tid] = start;
    const int node = b * 512 + tid;
    if (node < NNODES) {
        row_off[node] = start;
        cntA[node]    = hv;
        inv[node]     = rsqrtf((float)hv + 1.0f);
    }
    __syncthreads();
    for (int i = tid; i < cnt_b; i += 512) {
        unsigned t = tmp[tbase + i];
        int pos = atomicAdd(&lcur[(t >> 17) & 511], 1);
        col[pos] = (int)(t & 0x1FFFFu);
    }
}

// ============================================================
// Fused encoder v2b: x -> relu(xW1+b1) -> relu(..W2+b2) -> (..Wg0)*inv -> g8
// Conflict-free staging (quarter-wave = one 256B LDS row). Barrier added
// before the cross-wave g8 store (r12 bug fix).
// ============================================================
__global__ __launch_bounds__(512, 4) void k_enc(
    const float* __restrict__ x, const short* __restrict__ WT,
    const float* __restrict__ b1, const float* __restrict__ b2,
    const float* __restrict__ inv, unsigned char* __restrict__ g8, int M)
{
    __shared__ short As[128 * LDA];
    __shared__ short Bs[128 * LDA];

    const int tid = threadIdx.x;
    const int m0  = blockIdx.x * 128;

    // ---- stage x (fp32 -> bf16), conflict-free mapping ----
    #pragma unroll
    for (int i = 0; i < 4; ++i) {
        int u = tid + i * 512;
        int row = u >> 4, uc = (u & 15) << 3;
        int gr = min(m0 + row, M - 1);
        const float4* sp = (const float4*)(x + (size_t)gr * DIM + uc);
        float4 f0 = sp[0], f1 = sp[1];
        short t8[8] = { f2bf(f0.x), f2bf(f0.y), f2bf(f0.z), f2bf(f0.w),
                        f2bf(f1.x), f2bf(f1.y), f2bf(f1.z), f2bf(f1.w) };
        *(bf16x8*)&As[row * LDA + uc] = *(bf16x8*)t8;
    }

    const int wave = tid >> 6, lane = tid & 63;
    const int ml = lane & 15, quad = lane >> 4;
    const int w16 = wave * 16;

    #pragma unroll
    for (int mat = 0; mat < 3; ++mat) {
        if (mat > 0) __syncthreads();
        // stage Bs[mat], conflict-free mapping
        #pragma unroll
        for (int i = 0; i < 4; ++i) {
            int u = tid + i * 512;
            int n = u >> 4, kc = (u & 15) << 3;
            *(bf16x8*)&Bs[n * LDA + kc] =
                *(const bf16x8*)(WT + (size_t)mat * 16384 + n * DIM + kc);
        }
        __syncthreads();   // covers As staging (mat=0) and prior epilogues

        f32x4 acc[8] = {};
        #pragma unroll
        for (int kk = 0; kk < 4; ++kk) {
            const int k0 = kk * 32 + quad * 8;
            bf16x8 a = *(bf16x8*)&As[(w16 + ml) * LDA + k0];
            #pragma unroll
            for (int ni = 0; ni < 8; ++ni) {
                bf16x8 b = *(bf16x8*)&Bs[(ni * 16 + ml) * LDA + k0];
                acc[ni] = __builtin_amdgcn_mfma_f32_16x16x32_bf16(a, b, acc[ni], 0, 0, 0);
            }
        }
        #pragma unroll
        for (int ni = 0; ni < 8; ++ni) {
            const int colc = ni * 16 + ml;
            #pragma unroll
            for (int r = 0; r < 4; ++r) {
                const int rowl = w16 + quad * 4 + r;
                float v = acc[ni][r];
                if (mat == 0)      v = fmaxf(v + b1[colc], 0.f);
                else if (mat == 1) v = fmaxf(v + b2[colc], 0.f);
                else               v *= inv[min(m0 + rowl, M - 1)];
                As[rowl * LDA + colc] = f2bf(v);
            }
        }
    }
    __syncthreads();   // FIX(r12): store below reads rows written by other waves

    // ---- store g as fp8, conflict-free mapping ----
    #pragma unroll
    for (int i = 0; i < 4; ++i) {
        int u = tid + i * 512;
        int row = u >> 4, uc = (u & 15) << 3;
        int gr = m0 + row;
        if (gr < M) {
            bf16x8 t = *(bf16x8*)&As[row * LDA + uc];
            *(uint2*)(g8 + (size_t)gr * DIM + uc) = bf8_to_fp8(t);
        }
    }
}

// ============================================================
// gemm_mfma: g8 = fp8((A @ W)*inv[row]), W as bf16 W^T
// ============================================================
__global__ __launch_bounds__(256) void gemm_mfma(
    const short* __restrict__ A, const short* __restrict__ WT,
    const float* __restrict__ inv, unsigned char* __restrict__ g8, int M)
{
    __shared__ short As[128 * LDA];
    __shared__ short Bs[128 * LDA];

    const int tid = threadIdx.x;
    const int m0  = blockIdx.x * 128;

    #pragma unroll
    for (int i = 0; i < 8; ++i) {
        int idx = tid + i * 256;
        int row = idx >> 4, kg = (idx & 15) << 3;
        int r = min(m0 + row, M - 1);
        *(bf16x8*)&As[row * LDA + kg] = *(const bf16x8*)(A + (size_t)r * DIM + kg);
    }
    #pragma unroll
    for (int i = 0; i < 8; ++i) {
        int idx = tid + i * 256;
        int n = idx >> 4, kg = (idx & 15) << 3;
        *(bf16x8*)&Bs[n * LDA + kg] = *(const bf16x8*)(WT + n * DIM + kg);
    }
    __syncthreads();

    const int wave = tid >> 6, lane = tid & 63;
    const int ml = lane & 15, quad = lane >> 4;
    const int w32 = wave * 32;

    f32x4 acc[2][8] = {};
    #pragma unroll
    for (int kk = 0; kk < 4; ++kk) {
        const int k0 = kk * 32 + quad * 8;
        bf16x8 a0 = *(bf16x8*)&As[(w32 + ml) * LDA + k0];
        bf16x8 a1 = *(bf16x8*)&As[(w32 + 16 + ml) * LDA + k0];
        #pragma unroll
        for (int ni = 0; ni < 8; ++ni) {
            bf16x8 b = *(bf16x8*)&Bs[(ni * 16 + ml) * LDA + k0];
            acc[0][ni] = __builtin_amdgcn_mfma_f32_16x16x32_bf16(a0, b, acc[0][ni], 0, 0, 0);
            acc[1][ni] = __builtin_amdgcn_mfma_f32_16x16x32_bf16(a1, b, acc[1][ni], 0, 0, 0);
        }
    }
    __syncthreads();

    short* Cs = As;
    #pragma unroll
    for (int mi = 0; mi < 2; ++mi) {
        #pragma unroll
        for (int ni = 0; ni < 8; ++ni) {
            const int colc = ni * 16 + ml;
            #pragma unroll
            for (int r = 0; r < 4; ++r) {
                const int row = w32 + mi * 16 + quad * 4 + r;
                float v = acc[mi][ni][r] * inv[min(m0 + row, M - 1)];
                Cs[row * LDA + colc] = f2bf(v);
            }
        }
    }
    __syncthreads();
    #pragma unroll
    for (int i = 0; i < 8; ++i) {
        int idx = tid + i * 256;
        int row = idx >> 4, cg = (idx & 15) << 3;
        int gr = m0 + row;
        if (gr < M) {
            bf16x8 t = *(bf16x8*)&Cs[row * LDA + cg];
            *(uint2*)(g8 + (size_t)gr * DIM + cg) = bf8_to_fp8(t);
        }
    }
}

// ============================================================
// Aggregation v5 (fp8 rows): 4 nodes/wave, 16 lanes x uint2 per node,
// 8-edge unrolled leg for deeper MLP.
// ============================================================
__global__ __launch_bounds__(512) void k_agg(
    const unsigned char* __restrict__ g8v, const int* __restrict__ row_off,
    const int* __restrict__ cntA, const int* __restrict__ col,
    const float* __restrict__ inv, const float* __restrict__ bias,
    short* __restrict__ hout)
{
    const int wid  = blockIdx.x * 8 + (threadIdx.x >> 6);
    const int lane = threadIdx.x & 63;
    const int q    = lane >> 4;
    const int sl   = lane & 15;
    const int node = wid * 4 + q;
    if (node >= NNODES) return;

    const uint2* hp = (const uint2*)g8v;   // row = 16 x uint2 = 128 B
    uint2 us = hp[(size_t)node * 16 + sl];
    f32x2 p;
    float a0, a1, a2, a3, a4, a5, a6, a7;
    p = __builtin_amdgcn_cvt_pk_f32_fp8(us.x, false); a0 = p.x; a1 = p.y;
    p = __builtin_amdgcn_cvt_pk_f32_fp8(us.x, true);  a2 = p.x; a3 = p.y;
    p = __builtin_amdgcn_cvt_pk_f32_fp8(us.y, false); a4 = p.x; a5 = p.y;
    p = __builtin_amdgcn_cvt_pk_f32_fp8(us.y, true);  a6 = p.x; a7 = p.y;

    #define ACC8(v) \
        p = __builtin_amdgcn_cvt_pk_f32_fp8(v.x, false); a0 += p.x; a1 += p.y; \
        p = __builtin_amdgcn_cvt_pk_f32_fp8(v.x, true);  a2 += p.x; a3 += p.y; \
        p = __builtin_amdgcn_cvt_pk_f32_fp8(v.y, false); a4 += p.x; a5 += p.y; \
        p = __builtin_amdgcn_cvt_pk_f32_fp8(v.y, true);  a6 += p.x; a7 += p.y;

    const int s = row_off[node];
    const int e = s + cntA[node];
    int j = s;
    for (; j + 7 < e; j += 8) {
        uint2 v0 = hp[(size_t)col[j]     * 16 + sl];
        uint2 v1 = hp[(size_t)col[j + 1] * 16 + sl];
        uint2 v2 = hp[(size_t)col[j + 2] * 16 + sl];
        uint2 v3 = hp[(size_t)col[j + 3] * 16 + sl];
        uint2 v4 = hp[(size_t)col[j + 4] * 16 + sl];
        uint2 v5 = hp[(size_t)col[j + 5] * 16 + sl];
        uint2 v6 = hp[(size_t)col[j + 6] * 16 + sl];
        uint2 v7 = hp[(size_t)col[j + 7] * 16 + sl];
        ACC8(v0) ACC8(v1) ACC8(v2) ACC8(v3)
        ACC8(v4) ACC8(v5) ACC8(v6) ACC8(v7)
    }
    for (; j + 3 < e; j += 4) {
        uint2 v0 = hp[(size_t)col[j]     * 16 + sl];
        uint2 v1 = hp[(size_t)col[j + 1] * 16 + sl];
        uint2 v2 = hp[(size_t)col[j + 2] * 16 + sl];
        uint2 v3 = hp[(size_t)col[j + 3] * 16 + sl];
        ACC8(v0) ACC8(v1) ACC8(v2) ACC8(v3)
    }
    for (; j < e; ++j) {
        uint2 v = hp[(size_t)col[j] * 16 + sl];
        ACC8(v)
    }
    #undef ACC8

    const float scv = inv[node];
    const float4 bb0 = ((const float4*)bias)[sl * 2];
    const float4 bb1 = ((const float4*)bias)[sl * 2 + 1];
    short o[8];
    o[0] = f2bf(fmaxf(fmaf(a0, scv, bb0.x), 0.f));
    o[1] = f2bf(fmaxf(fmaf(a1, scv, bb0.y), 0.f));
    o[2] = f2bf(fmaxf(fmaf(a2, scv, bb0.z), 0.f));
    o[3] = f2bf(fmaxf(fmaf(a3, scv, bb0.w), 0.f));
    o[4] = f2bf(fmaxf(fmaf(a4, scv, bb1.x), 0.f));
    o[5] = f2bf(fmaxf(fmaf(a5, scv, bb1.y), 0.f));
    o[6] = f2bf(fmaxf(fmaf(a6, scv, bb1.z), 0.f));
    o[7] = f2bf(fmaxf(fmaf(a7, scv, bb1.w), 0.f));
    ((bf16x8*)hout)[(size_t)node * 16 + sl] = *(bf16x8*)o;
}

// ============================================================
// Global add pool: segmented atomic reduction (batch sorted).
// ============================================================
__global__ __launch_bounds__(512) void k_pool(
    const short* __restrict__ h, const int* __restrict__ batch,
    float* __restrict__ pooled)
{
    const int wave = threadIdx.x >> 6, lane = threadIdx.x & 63;
    const int node0 = blockIdx.x * 128 + wave * 16;
    const unsigned* hp = (const unsigned*)h;

    float gx = 0.f, gy = 0.f;
    int cg = -1;
    #pragma unroll 1
    for (int i = 0; i < 16; ++i) {
        const int node = node0 + i;
        if (node >= NNODES) break;
        const int g = batch[node];
        if (g != cg) {
            if (cg >= 0) {
                atomicAdd(pooled + (size_t)cg * DIM + lane * 2,     gx);
                atomicAdd(pooled + (size_t)cg * DIM + lane * 2 + 1, gy);
            }
            cg = g; gx = 0.f; gy = 0.f;
        }
        unsigned v = hp[(size_t)node * 64 + lane];
        gx += bf2f_lo(v);
        gy += bf2f_hi(v);
    }
    if (cg >= 0) {
        atomicAdd(pooled + (size_t)cg * DIM + lane * 2,     gx);
        atomicAdd(pooled + (size_t)cg * DIM + lane * 2 + 1, gy);
    }
}

// ============================================================
// Decoder: one wave per graph (64 blocks x 8 waves).
// ============================================================
__global__ __launch_bounds__(512) void k_dec(
    const float* __restrict__ pooled, const float* __restrict__ W1,
    const float* __restrict__ b1, const float* __restrict__ W2,
    const float* __restrict__ b2, float* __restrict__ out)
{
    __shared__ float pbuf[8][128];
    __shared__ float tbuf[8][128];
    const int wave = threadIdx.x >> 6, lane = threadIdx.x & 63;
    const int g = blockIdx.x * 8 + wave;

    float2 pv = *(const float2*)(pooled + (size_t)g * DIM + lane * 2);
    pbuf[wave][lane * 2]     = pv.x;
    pbuf[wave][lane * 2 + 1] = pv.y;
    __syncthreads();

    float t0 = 0.f, t1 = 0.f;
    #pragma unroll 8
    for (int k = 0; k < DIM; ++k) {
        float pk = pbuf[wave][k];
        float2 w = *(const float2*)(W1 + (size_t)k * DIM + lane * 2);
        t0 = fmaf(pk, w.x, t0);
        t1 = fmaf(pk, w.y, t1);
    }
    tbuf[wave][lane * 2]     = fmaxf(t0 + b1[lane * 2],     0.f);
    tbuf[wave][lane * 2 + 1] = fmaxf(t1 + b1[lane * 2 + 1], 0.f);
    __syncthreads();

    const int c = lane & 31, hh = lane >> 5;
    float part = 0.f;
    #pragma unroll 8
    for (int kk = 0; kk < 64; ++kk) {
        int k = hh * 64 + kk;
        part = fmaf(tbuf[wave][k], W2[(size_t)k * OUTD + c], part);
    }
    float other = __shfl_xor(part, 32, 64);
    if (hh == 0)
        out[(size_t)g * OUTD + c] = part + other + b2[c];
}

// ============================================================
extern "C" void kernel_launch(void* const* d_in, const int* in_sizes, int n_in,
                              void* d_out, int out_size, void* d_ws, size_t ws_size,
                              hipStream_t stream)
{
    const float* x      = (const float*)d_in[0];
    const int*   ei     = (const int*)d_in[1];
    const int*   batch  = (const int*)d_in[2];
    const float* enc_W1 = (const float*)d_in[3];
    const float* enc_b1 = (const float*)d_in[4];
    const float* enc_W2 = (const float*)d_in[5];
    const float* enc_b2 = (const float*)d_in[6];
    const float* gcn_W  = (const float*)d_in[7];
    const float* gcn_b  = (const float*)d_in[8];
    const float* dec_W1 = (const float*)d_in[9];
    const float* dec_b1 = (const float*)d_in[10];
    const float* dec_W2 = (const float*)d_in[11];
    const float* dec_b2 = (const float*)d_in[12];
    float* out = (float*)d_out;

    const int* src = ei;
    const int* dst = ei + NEDGES;

    char* p = (char*)d_ws;
    auto alloc = [&](size_t bytes) -> void* {
        void* r = (void*)p;
        p += (bytes + 255) & ~(size_t)255;
        return r;
    };
    short*         hw     = (short*)        alloc((size_t)NNODES * DIM * sizeof(short));
    unsigned char* g8     = (unsigned char*)alloc((size_t)NNODES * DIM);
    float*         inv    = (float*)        alloc((size_t)NNODES * sizeof(float));
    int*           row_off= (int*)          alloc((size_t)NNODES * sizeof(int));
    int*           cntA   = (int*)          alloc((size_t)NNODES * sizeof(int));
    int*           col    = (int*)          alloc((size_t)NBUCK2 * CAP * sizeof(int));
    unsigned*      tmp    = (unsigned*)     alloc((size_t)NBUCK2 * CAP * sizeof(unsigned));
    int*           gcur   = (int*)          alloc((size_t)NBUCK2 * sizeof(int));
    short*         WT     = (short*)        alloc((size_t)5 * DIM * DIM * sizeof(short));
    float*         pooled = (float*)        alloc((size_t)NGRAPH * DIM * sizeof(float));

    // ---- prep + CSR build ----
    k_prep   <<<(5 * 16384 + 255) / 256, 256, 0, stream>>>(enc_W1, enc_W2, gcn_W,
                                                           WT, gcur, pooled);
    k_scatter<<<SBLOCKS, 512, 0, stream>>>(src, dst, gcur, tmp);
    k_build  <<<NBUILD, 512, 0, stream>>>(tmp, gcur, row_off, cntA, inv, col);

    // ---- fused encoder: x -> g0 (fp8) ----
    k_enc<<<FBLOCKS, 512, 0, stream>>>(x, WT, enc_b1, enc_b2, inv, g8, NNODES);

    // ---- GCN layers: agg (g8 -> hw bf16) then gemm (hw -> g8 fp8) ----
    const int aggBlocks = (NNODES + 31) / 32;
    k_agg<<<aggBlocks, 512, 0, stream>>>(g8, row_off, cntA, col, inv, gcn_b, hw);
    gemm_mfma<<<FBLOCKS, 256, 0, stream>>>(hw, WT + 3 * 16384, inv, g8, NNODES);
    k_agg<<<aggBlocks, 512, 0, stream>>>(g8, row_off, cntA, col, inv, gcn_b + 128, hw);
    gemm_mfma<<<FBLOCKS, 256, 0, stream>>>(hw, WT + 4 * 16384, inv, g8, NNODES);
    k_agg<<<aggBlocks, 512, 0, stream>>>(g8, row_off, cntA, col, inv, gcn_b + 256, hw);

    // ---- pool + decoder ----
    k_pool<<<FBLOCKS, 512, 0, stream>>>(hw, batch, pooled);
    k_dec <<<NGRAPH / 8, 512, 0, stream>>>(pooled, dec_W1, dec_b1,
                                           dec_W2, dec_b2, out);
}